// Round 5
// baseline (762.859 us; speedup 1.0000x reference)
//
#include <hip/hip_runtime.h>
#include <cmath>

#define DI __device__ __forceinline__

constexpr int B_=2, S_=2048, E_=1024, H_=1344, NH_=4, DH_=336;
constexpr int BS_=B_*S_, H2_=2*H_;
constexpr int NG_=B_*NH_*S_;   // 16384

constexpr size_t N_X=(size_t)BS_*E_;
constexpr size_t N_WUP=(size_t)E_*H2_;
constexpr size_t N_WDN=(size_t)H_*E_;
constexpr size_t N_BSH=(size_t)BS_*H_;
constexpr size_t N_BSH2=(size_t)BS_*H2_;
constexpr size_t N_WH=5376, N_WG=16128, N_CK=4*H_;

// ---- ws layout (floats); identical to prior passing rounds ----
constexpr size_t O_IGB = 64;
constexpr size_t O_LOGF= O_IGB + NG_;
constexpr size_t O_AB  = O_LOGF+ NG_;
constexpr size_t O_MB  = O_AB  + NG_;
constexpr size_t O_MTB = O_MB  + NG_;
constexpr size_t O_CK  = O_MTB + NG_;
constexpr size_t O_CB  = O_CK  + N_CK;
constexpr size_t O_WQ  = O_CB  + H_;
constexpr size_t O_WK  = O_WQ  + N_WH;
constexpr size_t O_WV  = O_WK  + N_WH;
constexpr size_t O_WIG = O_WV  + N_WH;
constexpr size_t O_BIG = O_WIG + N_WG;
constexpr size_t O_WFG = O_BIG + 16;
constexpr size_t O_BFG = O_WFG + N_WG;
constexpr size_t O_LNW = O_BFG + 16;
constexpr size_t O_SKP = O_LNW + H_;
constexpr size_t O_FX  = O_SKP + H_;
constexpr size_t O_FWUP= O_FX  + N_X;
constexpr size_t O_FWDN= O_FWUP+ N_WUP;
constexpr size_t O_XIN = O_FWDN+ N_WDN;
constexpr size_t O_ACT = O_XIN + N_BSH2;
constexpr size_t O_QB  = O_ACT + N_BSH;
constexpr size_t O_KB  = O_QB  + N_BSH;
constexpr size_t O_VB  = O_KB  + N_BSH;
constexpr size_t O_HOUT= O_VB  + N_BSH;

// kfrag: [head][chunk=t/32][tile 0..41: 0-20=hi ks, 21-41=lo ks][l][8] bf16
// (B-frag 32x32x16: K[t0+(l&31)][ks*16+(l>>5)*8+j])
constexpr size_t KFRAG_SHORTS=(size_t)8*64*42*64*8;    // 11,010,048 (fits 2x KSPLIT region)
// vTf2: [head][chunk][sub=nt*2+th 0..21][l][8] bf16: V'[t0+th*16+(l>>5)*8+j][nt*32+(l&31)]
// n==336 -> 1.0 (rowsum), n>336 -> 0
constexpr size_t VT2_SHORTS=(size_t)8*64*22*64*8;      // 5,767,168

typedef __attribute__((ext_vector_type(8))) short bf16x8;
typedef __attribute__((ext_vector_type(4))) float f32x4;
typedef __attribute__((ext_vector_type(16))) float f32x16;

DI float bf2f(unsigned int u){union{unsigned int i;float f;}v;v.i=(u&0xffffu)<<16;return v.f;}
DI unsigned short f2bf(float f){union{float f;unsigned int i;}v;v.f=f;unsigned int x=v.i;
  return (unsigned short)((x+0x7fffu+((x>>16)&1u))>>16);}
DI float siluf(float x){return x/(1.f+expf(-x));}
DI float logsigf(float x){return (x>=0.f)?-log1pf(expf(-x)):x-log1pf(expf(x));}
DI void load4(const float* p, float* d){float4 v=*reinterpret_cast<const float4*>(p);
  d[0]=v.x;d[1]=v.y;d[2]=v.z;d[3]=v.w;}

// ---- dtype detect (fp32 proven; keep the guard) ----
__global__ __launch_bounds__(256) void detect_k(const unsigned short* __restrict__ xraw,
                                                int* __restrict__ flag){
  __shared__ int cnt_s;
  if(threadIdx.x==0) cnt_s=0;
  __syncthreads();
  int c=0;
  for(int i=threadIdx.x;i<2048;i+=256){
    const unsigned e=(xraw[i]>>7)&0xFFu;
    if(e>=0x90u) c++;
  }
  atomicAdd(&cnt_s,c);
  __syncthreads();
  if(threadIdx.x==0) *flag=(cnt_s>16)?0:1;
}

__global__ __launch_bounds__(256) void convert_k(const void* __restrict__ src,
                                                 float* __restrict__ dst,int n,
                                                 const int* __restrict__ flag){
  const int i=blockIdx.x*256+threadIdx.x;
  if(i>=n) return;
  if(*flag) dst[i]=bf2f(((const unsigned short*)src)[i]);
  else      dst[i]=((const float*)src)[i];
}

// ============================================================================
// A-fragment prep (16x16x32, for the two dense GEMMs)
// ============================================================================
__global__ __launch_bounds__(256) void aprep_k(const void* __restrict__ src,
                                               const int* __restrict__ flag,
                                               int kcn,int ldk,int total,
                                               unsigned short* __restrict__ hi,
                                               unsigned short* __restrict__ lo){
  const int slot=blockIdx.x*256+threadIdx.x;
  if(slot>=total) return;
  const int l=slot&63, rest=slot>>6;
  const int kc=rest%kcn, mt=rest/kcn;
  const int row=mt*16+(l&15), k0=kc*32+(l>>4)*8;
  const int fl=flag?*flag:0;
  float v[8];
  if(fl){
    const unsigned short* s=(const unsigned short*)src+(size_t)row*ldk+k0;
    const uint4 u=*reinterpret_cast<const uint4*>(s);
    v[0]=bf2f(u.x);v[1]=bf2f(u.x>>16);v[2]=bf2f(u.y);v[3]=bf2f(u.y>>16);
    v[4]=bf2f(u.z);v[5]=bf2f(u.z>>16);v[6]=bf2f(u.w);v[7]=bf2f(u.w>>16);
  }else{
    const float* s=(const float*)src+(size_t)row*ldk+k0;
    load4(s,v); load4(s+4,v+4);
  }
  unsigned short h8[8], l8[8];
#pragma unroll
  for(int j=0;j<8;j++){ h8[j]=f2bf(v[j]); l8[j]=f2bf(v[j]-bf2f(h8[j])); }
  uint4 ph,pl;
  ph.x=(unsigned)h8[0]|((unsigned)h8[1]<<16); ph.y=(unsigned)h8[2]|((unsigned)h8[3]<<16);
  ph.z=(unsigned)h8[4]|((unsigned)h8[5]<<16); ph.w=(unsigned)h8[6]|((unsigned)h8[7]<<16);
  pl.x=(unsigned)l8[0]|((unsigned)l8[1]<<16); pl.y=(unsigned)l8[2]|((unsigned)l8[3]<<16);
  pl.z=(unsigned)l8[4]|((unsigned)l8[5]<<16); pl.w=(unsigned)l8[6]|((unsigned)l8[7]<<16);
  *reinterpret_cast<uint4*>(&hi[(size_t)slot*8])=ph;
  *reinterpret_cast<uint4*>(&lo[(size_t)slot*8])=pl;
}

// ============================================================================
// B-fragment prep (16x16x32)
// ============================================================================
__global__ __launch_bounds__(256) void bprep_k(const void* __restrict__ src,
                                               const int* __restrict__ flag,
                                               int kcn,int ldn,int total,
                                               unsigned short* __restrict__ hi,
                                               unsigned short* __restrict__ lo){
  const int slot=blockIdx.x*256+threadIdx.x;
  if(slot>=total) return;
  const int l=slot&63, rest=slot>>6;
  const int kc=rest%kcn, nt=rest/kcn;
  const int col=nt*16+(l&15), row0=kc*32+(l>>4)*8;
  const int fl=flag?*flag:0;
  float v[8];
  if(fl){
    const unsigned short* s=(const unsigned short*)src;
#pragma unroll
    for(int j=0;j<8;j++) v[j]=bf2f(s[(size_t)(row0+j)*ldn+col]);
  }else{
    const float* s=(const float*)src;
#pragma unroll
    for(int j=0;j<8;j++) v[j]=s[(size_t)(row0+j)*ldn+col];
  }
  unsigned short h8[8], l8[8];
#pragma unroll
  for(int j=0;j<8;j++){ h8[j]=f2bf(v[j]); l8[j]=f2bf(v[j]-bf2f(h8[j])); }
  uint4 ph,pl;
  ph.x=(unsigned)h8[0]|((unsigned)h8[1]<<16); ph.y=(unsigned)h8[2]|((unsigned)h8[3]<<16);
  ph.z=(unsigned)h8[4]|((unsigned)h8[5]<<16); ph.w=(unsigned)h8[6]|((unsigned)h8[7]<<16);
  pl.x=(unsigned)l8[0]|((unsigned)l8[1]<<16); pl.y=(unsigned)l8[2]|((unsigned)l8[3]<<16);
  pl.z=(unsigned)l8[4]|((unsigned)l8[5]<<16); pl.w=(unsigned)l8[6]|((unsigned)l8[7]<<16);
  *reinterpret_cast<uint4*>(&hi[(size_t)slot*8])=ph;
  *reinterpret_cast<uint4*>(&lo[(size_t)slot*8])=pl;
}

// ============================================================================
// MFMA GEMM: 128x64 tile, split-bf16 3-chain, fp32 acc (unchanged, passing)
// ============================================================================
__global__ __launch_bounds__(256) void gemm_mfma_k(
    const unsigned short* __restrict__ Ahi, const unsigned short* __restrict__ Alo,
    const unsigned short* __restrict__ Bhi, const unsigned short* __restrict__ Blo,
    void* __restrict__ C, const int* __restrict__ flag, int kcn, int ldc){
  const int t=threadIdx.x, w=t>>6, l=t&63, lm=l&15, quad=l>>4;
  const int bn=blockIdx.x*64, bm=blockIdx.y*128;
  const int mt0=(bm>>4)+w, mt1=mt0+4;
  const size_t a0=((size_t)mt0*kcn)*512+(size_t)l*8;
  const size_t a1=((size_t)mt1*kcn)*512+(size_t)l*8;
  const size_t b0=((size_t)(bn>>4)*kcn)*512+(size_t)l*8;
  f32x4 acc[2][4];
#pragma unroll
  for(int g=0;g<2;g++)
#pragma unroll
    for(int nt=0;nt<4;nt++) acc[g][nt]={0.f,0.f,0.f,0.f};
  for(int kc=0;kc<kcn;kc++){
    const bf16x8 ah0=*reinterpret_cast<const bf16x8*>(&Ahi[a0+(size_t)kc*512]);
    const bf16x8 al0=*reinterpret_cast<const bf16x8*>(&Alo[a0+(size_t)kc*512]);
    const bf16x8 ah1=*reinterpret_cast<const bf16x8*>(&Ahi[a1+(size_t)kc*512]);
    const bf16x8 al1=*reinterpret_cast<const bf16x8*>(&Alo[a1+(size_t)kc*512]);
#pragma unroll
    for(int nt=0;nt<4;nt++){
      const size_t bo=b0+((size_t)nt*kcn+kc)*512;
      const bf16x8 bh=*reinterpret_cast<const bf16x8*>(&Bhi[bo]);
      const bf16x8 bl=*reinterpret_cast<const bf16x8*>(&Blo[bo]);
      acc[0][nt]=__builtin_amdgcn_mfma_f32_16x16x32_bf16(ah0,bh,acc[0][nt],0,0,0);
      acc[0][nt]=__builtin_amdgcn_mfma_f32_16x16x32_bf16(al0,bh,acc[0][nt],0,0,0);
      acc[0][nt]=__builtin_amdgcn_mfma_f32_16x16x32_bf16(ah0,bl,acc[0][nt],0,0,0);
      acc[1][nt]=__builtin_amdgcn_mfma_f32_16x16x32_bf16(ah1,bh,acc[1][nt],0,0,0);
      acc[1][nt]=__builtin_amdgcn_mfma_f32_16x16x32_bf16(al1,bh,acc[1][nt],0,0,0);
      acc[1][nt]=__builtin_amdgcn_mfma_f32_16x16x32_bf16(ah1,bl,acc[1][nt],0,0,0);
    }
  }
  const int bf=flag?*flag:0;
#pragma unroll
  for(int g=0;g<2;g++)
#pragma unroll
    for(int nt=0;nt<4;nt++)
#pragma unroll
      for(int r=0;r<4;r++){
        const size_t idx=(size_t)(bm+g*64+w*16+quad*4+r)*ldc+bn+nt*16+lm;
        if(bf) ((unsigned short*)C)[idx]=f2bf(acc[g][nt][r]);
        else   ((float*)C)[idx]=acc[g][nt][r];
      }
}

// ---- causal depthwise conv(K=4)+bias -> SiLU ----
__global__ __launch_bounds__(256) void conv_act_k(const float* __restrict__ xin,
                                                  const float* __restrict__ ck,
                                                  const float* __restrict__ cb,
                                                  float* __restrict__ act){
  const int i=blockIdx.x*256+threadIdx.x;
  if(i>=(int)N_BSH) return;
  const int bs=i/H_, h=i-bs*H_;
  const int b=bs/S_, s=bs-b*S_;
  float xc=cb[h];
#pragma unroll
  for(int w=0;w<4;w++){
    const int sr=s-3+w;
    if(sr>=0) xc+=xin[(size_t)(b*S_+sr)*H2_+h]*ck[w*H_+h];
  }
  act[(size_t)bs*H_+h]=siluf(xc);
}

// ---- headwise q/k/v ----
__global__ __launch_bounds__(256) void qkv_k(const float* __restrict__ act,
                                             const float* __restrict__ xin,
                                             const float* __restrict__ Wq,
                                             const float* __restrict__ Wk,
                                             const float* __restrict__ Wv,
                                             float* __restrict__ qb,float* __restrict__ kb,
                                             float* __restrict__ vb){
  const int i=blockIdx.x*256+threadIdx.x;
  if(i>=(int)N_BSH) return;
  const int bs=i/H_, h=i-bs*H_;
  const int b=bs/S_, s=bs-b*S_;
  const int ph=h>>2, o=h&3, base=ph*4;
  float q=0.f,k=0.f,v=0.f;
#pragma unroll
  for(int d=0;d<4;d++){
    const float a=act[(size_t)bs*H_+base+d];
    const float x=xin[(size_t)bs*H2_+base+d];
    q+=a*Wq[ph*16+d*4+o];
    k+=a*Wk[ph*16+d*4+o];
    v+=x*Wv[ph*16+d*4+o];
  }
  const int nh=h/DH_, dh=h-nh*DH_;
  const size_t off=((size_t)(b*NH_+nh)*S_+s)*DH_+dh;
  qb[off]=q; kb[off]=k; vb[off]=v;
}

// ============================================================================
// gates v2 — one wave per (b,s) row (passing, fast)
// ============================================================================
__global__ __launch_bounds__(256) void gates2_k(const float* __restrict__ qb,
                                                const float* __restrict__ kb,
                                                const float* __restrict__ vb,
                                                const float* __restrict__ Wig,
                                                const float* __restrict__ big,
                                                const float* __restrict__ Wfg,
                                                const float* __restrict__ bfg,
                                                float* __restrict__ igb,
                                                float* __restrict__ logfb){
  const int wid=(blockIdx.x*256+threadIdx.x)>>6;   // row = (b,s), 4096 waves
  const int l=threadIdx.x&63;
  if(wid>=BS_) return;
  const int b=wid>>11, s=wid&2047;
  float aI0=0.f,aI1=0.f,aI2=0.f,aI3=0.f;
  float aF0=0.f,aF1=0.f,aF2=0.f,aF3=0.f;
  for(int nh=0;nh<NH_;nh++){
    const size_t rb=((size_t)(b*NH_+nh)*S_+s)*DH_;
    const int hb=nh*DH_;
    for(int dh=l;dh<DH_;dh+=64){
      const int h=hb+dh;
      const float q=qb[rb+dh], k=kb[rb+dh], v=vb[rb+dh];
      const float4 wiq=*reinterpret_cast<const float4*>(&Wig[(size_t)h*4]);
      const float4 wik=*reinterpret_cast<const float4*>(&Wig[(size_t)(H_+h)*4]);
      const float4 wiv=*reinterpret_cast<const float4*>(&Wig[(size_t)(2*H_+h)*4]);
      const float4 wfq=*reinterpret_cast<const float4*>(&Wfg[(size_t)h*4]);
      const float4 wfk=*reinterpret_cast<const float4*>(&Wfg[(size_t)(H_+h)*4]);
      const float4 wfv=*reinterpret_cast<const float4*>(&Wfg[(size_t)(2*H_+h)*4]);
      aI0+=q*wiq.x+k*wik.x+v*wiv.x;
      aI1+=q*wiq.y+k*wik.y+v*wiv.y;
      aI2+=q*wiq.z+k*wik.z+v*wiv.z;
      aI3+=q*wiq.w+k*wik.w+v*wiv.w;
      aF0+=q*wfq.x+k*wfk.x+v*wfv.x;
      aF1+=q*wfq.y+k*wfk.y+v*wfv.y;
      aF2+=q*wfq.z+k*wfk.z+v*wfv.z;
      aF3+=q*wfq.w+k*wfk.w+v*wfv.w;
    }
  }
#pragma unroll
  for(int m=1;m<64;m<<=1){
    aI0+=__shfl_xor(aI0,m); aI1+=__shfl_xor(aI1,m);
    aI2+=__shfl_xor(aI2,m); aI3+=__shfl_xor(aI3,m);
    aF0+=__shfl_xor(aF0,m); aF1+=__shfl_xor(aF1,m);
    aF2+=__shfl_xor(aF2,m); aF3+=__shfl_xor(aF3,m);
  }
  if(l==0){
    const size_t o0=(size_t)(b*NH_+0)*S_+s;
    const size_t o1=(size_t)(b*NH_+1)*S_+s;
    const size_t o2=(size_t)(b*NH_+2)*S_+s;
    const size_t o3=(size_t)(b*NH_+3)*S_+s;
    igb[o0]=aI0+big[0]; igb[o1]=aI1+big[1];
    igb[o2]=aI2+big[2]; igb[o3]=aI3+big[3];
    logfb[o0]=logsigf(aF0+bfg[0]); logfb[o1]=logsigf(aF1+bfg[1]);
    logfb[o2]=logsigf(aF2+bfg[2]); logfb[o3]=logsigf(aF3+bfg[3]);
  }
}

// ============================================================================
// K prep v2: hi/lo bf16 in 32x32x16 B-frag layout, merged buffer.
// kfrag[head][c][ks]=hi, [head][c][21+ks]=lo; elem: K[c*32+(l&31)][ks*16+(l>>5)*8+j]
// ============================================================================
__global__ __launch_bounds__(256) void kprep2_k(const float* __restrict__ kb,
                                                unsigned short* __restrict__ kfrag){
  const int blk=blockIdx.x;                 // 8 heads * 64 chunks
  const int head=blk>>6, c=blk&63;
  const size_t obase=(size_t)(head*64+c)*42*512;
  for(int slot=threadIdx.x; slot<21*64; slot+=256){
    const int ks=slot>>6, ll=slot&63;
    const int tg=c*32+(ll&31), d0=ks*16+((ll>>5)<<3);
    float v[8];
    load4(&kb[((size_t)head*S_+tg)*DH_+d0],v);
    load4(&kb[((size_t)head*S_+tg)*DH_+d0+4],v+4);
    unsigned short hi8[8], lo8[8];
#pragma unroll
    for(int j=0;j<8;j++){
      hi8[j]=f2bf(v[j]);
      lo8[j]=f2bf(v[j]-bf2f(hi8[j]));
    }
    uint4 ph, pl;
    ph.x=(unsigned)hi8[0]|((unsigned)hi8[1]<<16); ph.y=(unsigned)hi8[2]|((unsigned)hi8[3]<<16);
    ph.z=(unsigned)hi8[4]|((unsigned)hi8[5]<<16); ph.w=(unsigned)hi8[6]|((unsigned)hi8[7]<<16);
    pl.x=(unsigned)lo8[0]|((unsigned)lo8[1]<<16); pl.y=(unsigned)lo8[2]|((unsigned)lo8[3]<<16);
    pl.z=(unsigned)lo8[4]|((unsigned)lo8[5]<<16); pl.w=(unsigned)lo8[6]|((unsigned)lo8[7]<<16);
    *reinterpret_cast<uint4*>(&kfrag[obase+(size_t)ks*512+(size_t)ll*8])=ph;
    *reinterpret_cast<uint4*>(&kfrag[obase+(size_t)(21+ks)*512+(size_t)ll*8])=pl;
  }
}

// ============================================================================
// V prep v2: V^T bf16 in 32x32x16 B-frag layout.
// vTf2[head][c][sub=nt*2+th]: elem V'[c*32+th*16+(l>>5)*8+j][nt*32+(l&31)]
// ============================================================================
__global__ __launch_bounds__(256) void vprep2_k(const float* __restrict__ vb,
                                                unsigned short* __restrict__ vTf2){
  const int blk=blockIdx.x;                 // 8 heads * 64 chunks
  const int head=blk>>6, c=blk&63;
  const size_t obase=(size_t)(head*64+c)*22*512;
  for(int slot=threadIdx.x; slot<22*64; slot+=256){
    const int sub=slot>>6, ll=slot&63;
    const int nt=sub>>1, th=sub&1;
    const int n=nt*32+(ll&31);
    const int t0=c*32+th*16+((ll>>5)<<3);
    unsigned short h8[8];
#pragma unroll
    for(int j=0;j<8;j++){
      float val;
      if(n<336)       val=vb[((size_t)head*S_+t0+j)*DH_+n];
      else if(n==336) val=1.f;
      else            val=0.f;
      h8[j]=f2bf(val);
    }
    uint4 pk;
    pk.x=(unsigned)h8[0]|((unsigned)h8[1]<<16); pk.y=(unsigned)h8[2]|((unsigned)h8[3]<<16);
    pk.z=(unsigned)h8[4]|((unsigned)h8[5]<<16); pk.w=(unsigned)h8[6]|((unsigned)h8[7]<<16);
    *reinterpret_cast<uint4*>(&vTf2[obase+(size_t)sub*512+(size_t)ll*8])=pk;
  }
}

// ---- parallel per-head scan ----
__global__ __launch_bounds__(256) void scan_k(const float* __restrict__ igb,
                                              const float* __restrict__ logfb,
                                              float* __restrict__ ab,float* __restrict__ Mb,
                                              float* __restrict__ mtb){
  const int head=blockIdx.x, t=threadIdx.x;
  __shared__ float sh[256];
  const float* lf=logfb+(size_t)head*S_;
  const float* ig=igb+(size_t)head*S_;
  float lc[8];
  float run=0.f;
#pragma unroll
  for(int i=0;i<8;i++){ run+=lf[t*8+i]; lc[i]=run; }
  sh[t]=run;
  for(int st=1;st<256;st<<=1){
    __syncthreads();
    const float v=(t>=st)?sh[t-st]:0.f;
    __syncthreads();
    sh[t]+=v;
  }
  __syncthreads();
  const float off=(t==0)?0.f:sh[t-1];
  __syncthreads();
  float av[8],mv[8],cv[8];
  float mrun=-1e30f;
#pragma unroll
  for(int i=0;i<8;i++){
    cv[i]=off+lc[i];
    av[i]=ig[t*8+i]-cv[i];
    mrun=fmaxf(mrun,av[i]);
    mv[i]=mrun;
  }
  sh[t]=mrun;
  for(int st=1;st<256;st<<=1){
    __syncthreads();
    const float v=(t>=st)?sh[t-st]:-1e30f;
    __syncthreads();
    sh[t]=fmaxf(sh[t],v);
  }
  __syncthreads();
  const float moff=(t==0)?-1e30f:sh[t-1];
#pragma unroll
  for(int i=0;i<8;i++){
    const float Mi=fmaxf(moff,mv[i]);
    const size_t j=(size_t)head*S_+t*8+i;
    ab[j]=av[i]; Mb[j]=Mi; mtb[j]=cv[i]+Mi;
  }
}

// ============================================================================
// mLSTM v11 — 32x32x16 MFMA, 128-row supertiles (4 waves x 32 rows), paired
// p<->15-p, 4-way seg split: 256 blocks x exactly 17 chunks. 2x LDS arithmetic
// intensity vs 16x16 (same 1KB frags, double MACs). Q hi/lo + 11x f32x16 acc
// in registers; global_load_lds DMA staging (64 tiles = 16/wave per chunk).
// ============================================================================
__global__ __launch_bounds__(256,1) void mlstm5_k(
    const float* __restrict__ qb, const unsigned short* __restrict__ kfrag,
    const unsigned short* __restrict__ vTf2,
    const float* __restrict__ ab, const float* __restrict__ Mb,
    float* __restrict__ part, float* __restrict__ rsum){
  const int bid=blockIdx.x;
  const int head=bid&7;                     // XCD pin: head h -> XCD h
  const int rest=bid>>3;                    // 0..31
  const int pairI=rest&7, seg=rest>>3;      // pair 0..7, seg 0..3
  const int t=threadIdx.x, w=t>>6, l=t&63;
  const int m32=l&31, half=l>>5;

  // LDS: double-buffered chunk staging: 64 tiles x 1KB (0-20 khi,21-41 klo,42-63 V)
  __shared__ short KV[2][64*512];
  __shared__ short Sc[4][32][40];           // per-wave S (C-layout write, A-frag read)

  const size_t hb=(size_t)head*S_;
  const float scale=0.05455447256f;         // 336^-0.5

  const int sbA=pairI, sbB=15-pairI;        // 128-row supertiles
  const int nAseg=sbA+1, nTot=17;           // uniform across all blocks

  bf16x8 qh[21], ql[21];
  f32x16 accO[11];
  float Mr[16];
  int ws0=sbA*128+w*32;

  const f32x16 z16={0.f,0.f,0.f,0.f,0.f,0.f,0.f,0.f,0.f,0.f,0.f,0.f,0.f,0.f,0.f,0.f};

  auto loadQ=[&](int ws0_){
    const float* qrow=qb+(hb+ws0_+m32)*DH_;
    const int kh8=half<<3;
#pragma unroll
    for(int ks=0;ks<21;ks++){
      float v[8];
      load4(qrow+ks*16+kh8,v);
      load4(qrow+ks*16+kh8+4,v+4);
#pragma unroll
      for(int j=0;j<8;j++){
        const unsigned short h=f2bf(v[j]);
        qh[ks][j]=(short)h;
        ql[ks][j]=(short)f2bf(v[j]-bf2f(h));
      }
    }
#pragma unroll
    for(int r=0;r<16;r++) Mr[r]=Mb[hb+ws0_+(r&3)+8*(r>>2)+4*half];
#pragma unroll
    for(int n=0;n<11;n++) accO[n]=z16;
  };

  // item i -> chunk index c (32-col chunks, stride-4 over seg)
  auto itemC=[&](int i)->int{
    return (i<nAseg)? (seg+4*i) : (seg+4*(i-nAseg));
  };

  // direct global->LDS DMA: 64 tiles x 1KB per chunk, 16 per wave.
  auto stage=[&](int buf,int c){
    const unsigned short* kc_=kfrag+((size_t)(head*64+c)*42)*512+(size_t)l*8;
    const unsigned short* vc_=vTf2 +((size_t)(head*64+c)*22)*512+(size_t)l*8;
#pragma unroll
    for(int j=0;j<16;j++){
      const int tr=w*16+j;
      const unsigned short* src=(tr<42)? kc_+(size_t)tr*512 : vc_+(size_t)(tr-42)*512;
      __builtin_amdgcn_global_load_lds(
        (const __attribute__((address_space(1))) unsigned int*)src,
        (__attribute__((address_space(3))) unsigned int*)&KV[buf][tr*512],
        16,0,0);
    }
  };

  auto compute=[&](int c,int buf){
    const int t0=c<<5;
    if(t0>ws0+31) return;                   // wave fully masked (uniform branch)
    const float al=ab[hb+t0+m32];
    const short* Kb=&KV[buf][0];
    f32x16 a0=z16, a1=z16, a2=z16;
#pragma unroll
    for(int ks=0;ks<21;ks++){
      const bf16x8 kh=*reinterpret_cast<const bf16x8*>(Kb+ks*512+l*8);
      const bf16x8 kl=*reinterpret_cast<const bf16x8*>(Kb+(21+ks)*512+l*8);
      a0=__builtin_amdgcn_mfma_f32_32x32x16_bf16(qh[ks],kh,a0,0,0,0);
      a1=__builtin_amdgcn_mfma_f32_32x32x16_bf16(ql[ks],kh,a1,0,0,0);
      a2=__builtin_amdgcn_mfma_f32_32x32x16_bf16(qh[ks],kl,a2,0,0,0);
    }
#pragma unroll
    for(int r=0;r<16;r++){
      const int lr=(r&3)+8*(r>>2)+4*half;   // local row 0..31
      const float qk=a0[r]+a1[r]+a2[r];
      const float e=fminf(al-Mr[r],0.f);
      const float msk=(t0+m32<=ws0+lr)?1.f:0.f;
      Sc[w][lr][m32]=(short)f2bf(msk*(qk*scale*expf(e)));
    }
    const bf16x8 sa0=*reinterpret_cast<const bf16x8*>(&Sc[w][m32][half*8]);
    const bf16x8 sa1=*reinterpret_cast<const bf16x8*>(&Sc[w][m32][half*8+16]);
#pragma unroll
    for(int nt=0;nt<11;nt++){
      const bf16x8 v0=*reinterpret_cast<const bf16x8*>(Kb+(42+nt*2)*512+l*8);
      const bf16x8 v1=*reinterpret_cast<const bf16x8*>(Kb+(42+nt*2+1)*512+l*8);
      accO[nt]=__builtin_amdgcn_mfma_f32_32x32x16_bf16(sa0,v0,accO[nt],0,0,0);
      accO[nt]=__builtin_amdgcn_mfma_f32_32x32x16_bf16(sa1,v1,accO[nt],0,0,0);
    }
  };

  auto epilogue=[&](){
#pragma unroll
    for(int nt=0;nt<11;nt++){
      const int col=nt*32+m32;
#pragma unroll
      for(int r=0;r<16;r++){
        const int rowg=ws0+(r&3)+8*(r>>2)+4*half;
        const float val=accO[nt][r];
        if(col<336){ if(val!=0.f) atomicAdd(&part[((size_t)head*2048+rowg)*336+col],val); }
        else if(col==336){ if(val!=0.f) atomicAdd(&rsum[(size_t)head*2048+rowg],val); }
      }
    }
  };

  loadQ(ws0);
  stage(0,itemC(0));
  __syncthreads();                          // drains vmcnt: buffer 0 ready
  int cur=0;
  for(int i=0;i<nTot;i++){
    if(i+1<nTot) stage(cur^1,itemC(i+1));   // DMA next chunk into back buffer
    compute(itemC(i),cur);
    if(i==nAseg-1){                         // tile switch: A done
      epilogue();
      ws0=sbB*128+w*32;
      loadQ(ws0);
    }
    __syncthreads();                        // drain DMA + cross-wave sync
    cur^=1;
  }
  epilogue();                               // tile B
}

// ============================================================================
// finalize: n-normalizer + per-head groupnorm + hout write (proven).
// ============================================================================
__global__ __launch_bounds__(256) void finalize_k(const float* __restrict__ part,
                                                  const float* __restrict__ rsum,
                                                  const float* __restrict__ mtb,
                                                  const float* __restrict__ lnw,
                                                  float* __restrict__ hout){
  const int sblk=blockIdx.x, head=blockIdx.y;
  const int bI=head>>2, nh=head&3;
  const int s0=sblk*32;
  const int t=threadIdx.x, row=t>>3, sub=t&7;
  __shared__ float red1[32][8], red2[32][8];
  __shared__ float mu_s[32], rs_s[32], inv_s[32];
  const size_t pbase=(size_t)head*2048+s0;
  const float* prow=part+(pbase+row)*336;
  float s1=0.f,s2=0.f;
  for(int c=sub;c<336;c+=8){ const float v=prow[c]; s1+=v; s2+=v*v; }
  red1[row][sub]=s1; red2[row][sub]=s2;
  __syncthreads();
  if(sub==0){
    float a1=0.f,a2=0.f;
#pragma unroll
    for(int j=0;j<8;j++){ a1+=red1[row][j]; a2+=red2[row][j]; }
    const float mt=mtb[(size_t)head*S_+s0+row];
    const float nn=fmaxf(fabsf(rsum[pbase+row]), expf(fminf(fmaxf(-mt,-60.f),60.f)));
    const float inv=1.f/(nn+1e-6f);
    const float mu=a1*inv/336.f;
    const float var=a2*inv*inv/336.f-mu*mu;
    inv_s[row]=inv; mu_s[row]=mu;
    rs_s[row]=rsqrtf(fmaxf(var,0.f)+1e-5f);
  }
  __syncthreads();
  const float inv=inv_s[row], mu=mu_s[row], rs=rs_s[row];
  float* orow=hout+((size_t)(bI*S_+s0+row))*H_+nh*DH_;
  for(int c=sub;c<336;c+=8)
    orow[c]=(prow[c]*inv-mu)*rs*lnw[nh*DH_+c];
}

// ---- h_state = (h_out + skip*act) * silu(z) ----
__global__ __launch_bounds__(256) void hstate_k(const float* __restrict__ hout,
                                                const float* __restrict__ act,
                                                const float* __restrict__ xin,
                                                const float* __restrict__ skip,
                                                float* __restrict__ hs){
  const int i=blockIdx.x*256+threadIdx.x;
  if(i>=(int)N_BSH) return;
  const int bs=i/H_, h=i-bs*H_;
  const float z=xin[(size_t)bs*H2_+H_+h];
  hs[(size_t)bs*H_+h]=(hout[(size_t)bs*H_+h]+skip[h]*act[(size_t)bs*H_+h])*siluf(z);
}

// ============================================================================
extern "C" void kernel_launch(void* const* d_in, const int* in_sizes, int n_in,
                              void* d_out, int out_size, void* d_ws, size_t ws_size,
                              hipStream_t stream){
  float* ws=(float*)d_ws;
  int* flag=(int*)ws;

  float* igb  = ws+O_IGB;
  float* logfb= ws+O_LOGF;
  float* ab   = ws+O_AB;
  float* Mbuf = ws+O_MB;
  float* mtb  = ws+O_MTB;
  float* f_ck = ws+O_CK;
  float* f_cb = ws+O_CB;
  float* f_wq = ws+O_WQ;
  float* f_wk = ws+O_WK;
  float* f_wv = ws+O_WV;
  float* f_wig= ws+O_WIG;
  float* f_big= ws+O_BIG;
  float* f_wfg= ws+O_WFG;
  float* f_bfg= ws+O_BFG;
  float* f_lnw= ws+O_LNW;
  float* f_skp= ws+O_SKP;
  float* xin  = ws+O_XIN;
  float* act  = ws+O_ACT;
  float* qb   = ws+O_QB;
  float* kb   = ws+O_KB;
  float* vb   = ws+O_VB;
  float* hout = ws+O_HOUT;
  float* hs   = qb;                            // alias: q dead after mlstm5_k

  unsigned short* xhi  =(unsigned short*)(ws+O_FX);   unsigned short* xlo  =xhi+N_X;
  unsigned short* wuphi=(unsigned short*)(ws+O_FWUP); unsigned short* wuplo=wuphi+N_WUP;
  unsigned short* wdnhi=(unsigned short*)(ws+O_FWDN); unsigned short* wdnlo=wdnhi+N_WDN;
  unsigned short* kfrag=(unsigned short*)(ws+O_FX);   // x/wup frags dead after up-gemm
  unsigned short* vTf2=(unsigned short*)kb;    // kb dead after gates+kprep
  unsigned short* hshi=(unsigned short*)kb;    // vTf2 dead after mlstm5_k
  unsigned short* hslo=hshi+N_BSH;
  float* partb=vb;                             // vb dead after vprep
  float* rsumb=igb;                            // igb dead after scan_k

  detect_k<<<1,256,0,stream>>>((const unsigned short*)d_in[0],flag);
  auto cvt=[&](int idx,float* dst,size_t n){
    convert_k<<<(int)((n+255)/256),256,0,stream>>>(d_in[idx],dst,(int)n,flag);
  };
  cvt(2,f_ck,N_CK);  cvt(3,f_cb,H_);
  cvt(4,f_wq,N_WH); cvt(5,f_wk,N_WH);   cvt(6,f_wv,N_WH);  cvt(7,f_wig,N_WG);
  cvt(8,f_big,4);   cvt(9,f_wfg,N_WG);  cvt(10,f_bfg,4);   cvt(11,f_lnw,H_);
  cvt(12,f_skp,H_);

  // up-GEMM: xin = x @ Wup  (M=4096,K=1024 kcn=32, N=2688)
  aprep_k<<<(256*32*64+255)/256,256,0,stream>>>(d_in[0],flag,32,1024,256*32*64,xhi,xlo);
  bprep_k<<<(168*32*64+255)/256,256,0,stream>>>(d_in[1],flag,32,2688,168*32*64,wuphi,wuplo);
  gemm_mfma_k<<<dim3(2688/64,4096/128),256,0,stream>>>(xhi,xlo,wuphi,wuplo,xin,nullptr,32,H2_);

  conv_act_k<<<(int)((N_BSH+255)/256),256,0,stream>>>(xin,f_ck,f_cb,act);
  qkv_k<<<(int)((N_BSH+255)/256),256,0,stream>>>(act,xin,f_wq,f_wk,f_wv,qb,kb,vb);
  // gates v2: one wave per (b,s) row, 4096 waves
  gates2_k<<<(BS_*64+255)/256,256,0,stream>>>(qb,kb,vb,f_wig,f_big,f_wfg,f_bfg,igb,logfb);
  kprep2_k<<<8*64,256,0,stream>>>(kb,kfrag);
  vprep2_k<<<8*64,256,0,stream>>>(vb,vTf2);
  // wdn frags (independent; region untouched by kfrag: 22MB < 27.8MB offset)
  bprep_k<<<(64*42*64+255)/256,256,0,stream>>>(d_in[13],flag,42,1024,64*42*64,wdnhi,wdnlo);
  scan_k<<<B_*NH_,256,0,stream>>>(igb,logfb,ab,Mbuf,mtb);
  hipMemsetAsync(partb,0,N_BSH*sizeof(float),stream);
  hipMemsetAsync(rsumb,0,(size_t)NG_*sizeof(float),stream);
  // mLSTM v11: 256 blocks = 8 heads x 8 pairs x 4 seg; 17 chunks/block uniform
  mlstm5_k<<<256,256,0,stream>>>(qb,kfrag,vTf2,ab,Mbuf,partb,rsumb);
  finalize_k<<<dim3(S_/32,B_*NH_),256,0,stream>>>(partb,rsumb,mtb,f_lnw,hout);
  hstate_k<<<(int)((N_BSH+255)/256),256,0,stream>>>(hout,act,xin,f_skp,hs);
  // down-GEMM: out = hs @ Wdn  (M=4096,K=1344 kcn=42, N=1024), direct to d_out
  aprep_k<<<(256*42*64+255)/256,256,0,stream>>>(hs,nullptr,42,1344,256*42*64,hshi,hslo);
  gemm_mfma_k<<<dim3(1024/64,4096/128),256,0,stream>>>(hshi,hslo,wdnhi,wdnlo,d_out,flag,42,E_);
}

// Round 6
// 524.927 us; speedup vs baseline: 1.4533x; 1.4533x over previous
//
#include <hip/hip_runtime.h>
#include <cmath>

#define DI __device__ __forceinline__

constexpr int B_=2, S_=2048, E_=1024, H_=1344, NH_=4, DH_=336;
constexpr int BS_=B_*S_, H2_=2*H_;
constexpr int NG_=B_*NH_*S_;   // 16384

constexpr size_t N_X=(size_t)BS_*E_;
constexpr size_t N_WUP=(size_t)E_*H2_;
constexpr size_t N_WDN=(size_t)H_*E_;
constexpr size_t N_BSH=(size_t)BS_*H_;
constexpr size_t N_BSH2=(size_t)BS_*H2_;
constexpr size_t N_WH=5376, N_WG=16128, N_CK=4*H_;

// ---- ws layout (floats); identical to prior passing rounds ----
constexpr size_t O_IGB = 64;
constexpr size_t O_LOGF= O_IGB + NG_;
constexpr size_t O_AB  = O_LOGF+ NG_;
constexpr size_t O_MB  = O_AB  + NG_;
constexpr size_t O_MTB = O_MB  + NG_;
constexpr size_t O_CK  = O_MTB + NG_;
constexpr size_t O_CB  = O_CK  + N_CK;
constexpr size_t O_WQ  = O_CB  + H_;
constexpr size_t O_WK  = O_WQ  + N_WH;
constexpr size_t O_WV  = O_WK  + N_WH;
constexpr size_t O_WIG = O_WV  + N_WH;
constexpr size_t O_BIG = O_WIG + N_WG;
constexpr size_t O_WFG = O_BIG + 16;
constexpr size_t O_BFG = O_WFG + N_WG;
constexpr size_t O_LNW = O_BFG + 16;
constexpr size_t O_SKP = O_LNW + H_;
constexpr size_t O_FX  = O_SKP + H_;
constexpr size_t O_FWUP= O_FX  + N_X;
constexpr size_t O_FWDN= O_FWUP+ N_WUP;
constexpr size_t O_XIN = O_FWDN+ N_WDN;
constexpr size_t O_ACT = O_XIN + N_BSH2;
constexpr size_t O_QB  = O_ACT + N_BSH;
constexpr size_t O_KB  = O_QB  + N_BSH;
constexpr size_t O_VB  = O_KB  + N_BSH;
constexpr size_t O_HOUT= O_VB  + N_BSH;

// khi/klo: [head][tile=t/16][dc=0..10][l][8] bf16 (B-frag 16x16x32)
constexpr size_t KSPLIT_SHORTS=(size_t)8*128*11*64*8;  // 5,767,168
// vTf: [head][tc=t/32][ntg=0..21][l][8] bf16; n==336 -> 1.0 (rowsum), n>336 -> 0
constexpr size_t VT_SHORTS=(size_t)8*64*22*64*8;       // 5,767,168

typedef __attribute__((ext_vector_type(8))) short bf16x8;
typedef __attribute__((ext_vector_type(4))) float f32x4;

DI float bf2f(unsigned int u){union{unsigned int i;float f;}v;v.i=(u&0xffffu)<<16;return v.f;}
DI unsigned short f2bf(float f){union{float f;unsigned int i;}v;v.f=f;unsigned int x=v.i;
  return (unsigned short)((x+0x7fffu+((x>>16)&1u))>>16);}
DI float siluf(float x){return x/(1.f+expf(-x));}
DI float logsigf(float x){return (x>=0.f)?-log1pf(expf(-x)):x-log1pf(expf(x));}
DI void load4(const float* p, float* d){float4 v=*reinterpret_cast<const float4*>(p);
  d[0]=v.x;d[1]=v.y;d[2]=v.z;d[3]=v.w;}

// ---- dtype detect (fp32 proven; keep the guard) ----
__global__ __launch_bounds__(256) void detect_k(const unsigned short* __restrict__ xraw,
                                                int* __restrict__ flag){
  __shared__ int cnt_s;
  if(threadIdx.x==0) cnt_s=0;
  __syncthreads();
  int c=0;
  for(int i=threadIdx.x;i<2048;i+=256){
    const unsigned e=(xraw[i]>>7)&0xFFu;
    if(e>=0x90u) c++;
  }
  atomicAdd(&cnt_s,c);
  __syncthreads();
  if(threadIdx.x==0) *flag=(cnt_s>16)?0:1;
}

__global__ __launch_bounds__(256) void convert_k(const void* __restrict__ src,
                                                 float* __restrict__ dst,int n,
                                                 const int* __restrict__ flag){
  const int i=blockIdx.x*256+threadIdx.x;
  if(i>=n) return;
  if(*flag) dst[i]=bf2f(((const unsigned short*)src)[i]);
  else      dst[i]=((const float*)src)[i];
}

// ============================================================================
// A-fragment prep
// ============================================================================
__global__ __launch_bounds__(256) void aprep_k(const void* __restrict__ src,
                                               const int* __restrict__ flag,
                                               int kcn,int ldk,int total,
                                               unsigned short* __restrict__ hi,
                                               unsigned short* __restrict__ lo){
  const int slot=blockIdx.x*256+threadIdx.x;
  if(slot>=total) return;
  const int l=slot&63, rest=slot>>6;
  const int kc=rest%kcn, mt=rest/kcn;
  const int row=mt*16+(l&15), k0=kc*32+(l>>4)*8;
  const int fl=flag?*flag:0;
  float v[8];
  if(fl){
    const unsigned short* s=(const unsigned short*)src+(size_t)row*ldk+k0;
    const uint4 u=*reinterpret_cast<const uint4*>(s);
    v[0]=bf2f(u.x);v[1]=bf2f(u.x>>16);v[2]=bf2f(u.y);v[3]=bf2f(u.y>>16);
    v[4]=bf2f(u.z);v[5]=bf2f(u.z>>16);v[6]=bf2f(u.w);v[7]=bf2f(u.w>>16);
  }else{
    const float* s=(const float*)src+(size_t)row*ldk+k0;
    load4(s,v); load4(s+4,v+4);
  }
  unsigned short h8[8], l8[8];
#pragma unroll
  for(int j=0;j<8;j++){ h8[j]=f2bf(v[j]); l8[j]=f2bf(v[j]-bf2f(h8[j])); }
  uint4 ph,pl;
  ph.x=(unsigned)h8[0]|((unsigned)h8[1]<<16); ph.y=(unsigned)h8[2]|((unsigned)h8[3]<<16);
  ph.z=(unsigned)h8[4]|((unsigned)h8[5]<<16); ph.w=(unsigned)h8[6]|((unsigned)h8[7]<<16);
  pl.x=(unsigned)l8[0]|((unsigned)l8[1]<<16); pl.y=(unsigned)l8[2]|((unsigned)l8[3]<<16);
  pl.z=(unsigned)l8[4]|((unsigned)l8[5]<<16); pl.w=(unsigned)l8[6]|((unsigned)l8[7]<<16);
  *reinterpret_cast<uint4*>(&hi[(size_t)slot*8])=ph;
  *reinterpret_cast<uint4*>(&lo[(size_t)slot*8])=pl;
}

// ============================================================================
// B-fragment prep
// ============================================================================
__global__ __launch_bounds__(256) void bprep_k(const void* __restrict__ src,
                                               const int* __restrict__ flag,
                                               int kcn,int ldn,int total,
                                               unsigned short* __restrict__ hi,
                                               unsigned short* __restrict__ lo){
  const int slot=blockIdx.x*256+threadIdx.x;
  if(slot>=total) return;
  const int l=slot&63, rest=slot>>6;
  const int kc=rest%kcn, nt=rest/kcn;
  const int col=nt*16+(l&15), row0=kc*32+(l>>4)*8;
  const int fl=flag?*flag:0;
  float v[8];
  if(fl){
    const unsigned short* s=(const unsigned short*)src;
#pragma unroll
    for(int j=0;j<8;j++) v[j]=bf2f(s[(size_t)(row0+j)*ldn+col]);
  }else{
    const float* s=(const float*)src;
#pragma unroll
    for(int j=0;j<8;j++) v[j]=s[(size_t)(row0+j)*ldn+col];
  }
  unsigned short h8[8], l8[8];
#pragma unroll
  for(int j=0;j<8;j++){ h8[j]=f2bf(v[j]); l8[j]=f2bf(v[j]-bf2f(h8[j])); }
  uint4 ph,pl;
  ph.x=(unsigned)h8[0]|((unsigned)h8[1]<<16); ph.y=(unsigned)h8[2]|((unsigned)h8[3]<<16);
  ph.z=(unsigned)h8[4]|((unsigned)h8[5]<<16); ph.w=(unsigned)h8[6]|((unsigned)h8[7]<<16);
  pl.x=(unsigned)l8[0]|((unsigned)l8[1]<<16); pl.y=(unsigned)l8[2]|((unsigned)l8[3]<<16);
  pl.z=(unsigned)l8[4]|((unsigned)l8[5]<<16); pl.w=(unsigned)l8[6]|((unsigned)l8[7]<<16);
  *reinterpret_cast<uint4*>(&hi[(size_t)slot*8])=ph;
  *reinterpret_cast<uint4*>(&lo[(size_t)slot*8])=pl;
}

// ============================================================================
// MFMA GEMM: 128x64 tile, split-bf16 3-chain, fp32 acc
// ============================================================================
__global__ __launch_bounds__(256) void gemm_mfma_k(
    const unsigned short* __restrict__ Ahi, const unsigned short* __restrict__ Alo,
    const unsigned short* __restrict__ Bhi, const unsigned short* __restrict__ Blo,
    void* __restrict__ C, const int* __restrict__ flag, int kcn, int ldc){
  const int t=threadIdx.x, w=t>>6, l=t&63, lm=l&15, quad=l>>4;
  const int bn=blockIdx.x*64, bm=blockIdx.y*128;
  const int mt0=(bm>>4)+w, mt1=mt0+4;
  const size_t a0=((size_t)mt0*kcn)*512+(size_t)l*8;
  const size_t a1=((size_t)mt1*kcn)*512+(size_t)l*8;
  const size_t b0=((size_t)(bn>>4)*kcn)*512+(size_t)l*8;
  f32x4 acc[2][4];
#pragma unroll
  for(int g=0;g<2;g++)
#pragma unroll
    for(int nt=0;nt<4;nt++) acc[g][nt]={0.f,0.f,0.f,0.f};
  for(int kc=0;kc<kcn;kc++){
    const bf16x8 ah0=*reinterpret_cast<const bf16x8*>(&Ahi[a0+(size_t)kc*512]);
    const bf16x8 al0=*reinterpret_cast<const bf16x8*>(&Alo[a0+(size_t)kc*512]);
    const bf16x8 ah1=*reinterpret_cast<const bf16x8*>(&Ahi[a1+(size_t)kc*512]);
    const bf16x8 al1=*reinterpret_cast<const bf16x8*>(&Alo[a1+(size_t)kc*512]);
#pragma unroll
    for(int nt=0;nt<4;nt++){
      const size_t bo=b0+((size_t)nt*kcn+kc)*512;
      const bf16x8 bh=*reinterpret_cast<const bf16x8*>(&Bhi[bo]);
      const bf16x8 bl=*reinterpret_cast<const bf16x8*>(&Blo[bo]);
      acc[0][nt]=__builtin_amdgcn_mfma_f32_16x16x32_bf16(ah0,bh,acc[0][nt],0,0,0);
      acc[0][nt]=__builtin_amdgcn_mfma_f32_16x16x32_bf16(al0,bh,acc[0][nt],0,0,0);
      acc[0][nt]=__builtin_amdgcn_mfma_f32_16x16x32_bf16(ah0,bl,acc[0][nt],0,0,0);
      acc[1][nt]=__builtin_amdgcn_mfma_f32_16x16x32_bf16(ah1,bh,acc[1][nt],0,0,0);
      acc[1][nt]=__builtin_amdgcn_mfma_f32_16x16x32_bf16(al1,bh,acc[1][nt],0,0,0);
      acc[1][nt]=__builtin_amdgcn_mfma_f32_16x16x32_bf16(ah1,bl,acc[1][nt],0,0,0);
    }
  }
  const int bf=flag?*flag:0;
#pragma unroll
  for(int g=0;g<2;g++)
#pragma unroll
    for(int nt=0;nt<4;nt++)
#pragma unroll
      for(int r=0;r<4;r++){
        const size_t idx=(size_t)(bm+g*64+w*16+quad*4+r)*ldc+bn+nt*16+lm;
        if(bf) ((unsigned short*)C)[idx]=f2bf(acc[g][nt][r]);
        else   ((float*)C)[idx]=acc[g][nt][r];
      }
}

// ---- causal depthwise conv(K=4)+bias -> SiLU ----
__global__ __launch_bounds__(256) void conv_act_k(const float* __restrict__ xin,
                                                  const float* __restrict__ ck,
                                                  const float* __restrict__ cb,
                                                  float* __restrict__ act){
  const int i=blockIdx.x*256+threadIdx.x;
  if(i>=(int)N_BSH) return;
  const int bs=i/H_, h=i-bs*H_;
  const int b=bs/S_, s=bs-b*S_;
  float xc=cb[h];
#pragma unroll
  for(int w=0;w<4;w++){
    const int sr=s-3+w;
    if(sr>=0) xc+=xin[(size_t)(b*S_+sr)*H2_+h]*ck[w*H_+h];
  }
  act[(size_t)bs*H_+h]=siluf(xc);
}

// ---- headwise q/k/v ----
__global__ __launch_bounds__(256) void qkv_k(const float* __restrict__ act,
                                             const float* __restrict__ xin,
                                             const float* __restrict__ Wq,
                                             const float* __restrict__ Wk,
                                             const float* __restrict__ Wv,
                                             float* __restrict__ qb,float* __restrict__ kb,
                                             float* __restrict__ vb){
  const int i=blockIdx.x*256+threadIdx.x;
  if(i>=(int)N_BSH) return;
  const int bs=i/H_, h=i-bs*H_;
  const int b=bs/S_, s=bs-b*S_;
  const int ph=h>>2, o=h&3, base=ph*4;
  float q=0.f,k=0.f,v=0.f;
#pragma unroll
  for(int d=0;d<4;d++){
    const float a=act[(size_t)bs*H_+base+d];
    const float x=xin[(size_t)bs*H2_+base+d];
    q+=a*Wq[ph*16+d*4+o];
    k+=a*Wk[ph*16+d*4+o];
    v+=x*Wv[ph*16+d*4+o];
  }
  const int nh=h/DH_, dh=h-nh*DH_;
  const size_t off=((size_t)(b*NH_+nh)*S_+s)*DH_+dh;
  qb[off]=q; kb[off]=k; vb[off]=v;
}

// ============================================================================
// gates v2 — one wave per (b,s) row (passing, fast)
// ============================================================================
__global__ __launch_bounds__(256) void gates2_k(const float* __restrict__ qb,
                                                const float* __restrict__ kb,
                                                const float* __restrict__ vb,
                                                const float* __restrict__ Wig,
                                                const float* __restrict__ big,
                                                const float* __restrict__ Wfg,
                                                const float* __restrict__ bfg,
                                                float* __restrict__ igb,
                                                float* __restrict__ logfb){
  const int wid=(blockIdx.x*256+threadIdx.x)>>6;   // row = (b,s), 4096 waves
  const int l=threadIdx.x&63;
  if(wid>=BS_) return;
  const int b=wid>>11, s=wid&2047;
  float aI0=0.f,aI1=0.f,aI2=0.f,aI3=0.f;
  float aF0=0.f,aF1=0.f,aF2=0.f,aF3=0.f;
  for(int nh=0;nh<NH_;nh++){
    const size_t rb=((size_t)(b*NH_+nh)*S_+s)*DH_;
    const int hb=nh*DH_;
    for(int dh=l;dh<DH_;dh+=64){
      const int h=hb+dh;
      const float q=qb[rb+dh], k=kb[rb+dh], v=vb[rb+dh];
      const float4 wiq=*reinterpret_cast<const float4*>(&Wig[(size_t)h*4]);
      const float4 wik=*reinterpret_cast<const float4*>(&Wig[(size_t)(H_+h)*4]);
      const float4 wiv=*reinterpret_cast<const float4*>(&Wig[(size_t)(2*H_+h)*4]);
      const float4 wfq=*reinterpret_cast<const float4*>(&Wfg[(size_t)h*4]);
      const float4 wfk=*reinterpret_cast<const float4*>(&Wfg[(size_t)(H_+h)*4]);
      const float4 wfv=*reinterpret_cast<const float4*>(&Wfg[(size_t)(2*H_+h)*4]);
      aI0+=q*wiq.x+k*wik.x+v*wiv.x;
      aI1+=q*wiq.y+k*wik.y+v*wiv.y;
      aI2+=q*wiq.z+k*wik.z+v*wiv.z;
      aI3+=q*wiq.w+k*wik.w+v*wiv.w;
      aF0+=q*wfq.x+k*wfk.x+v*wfv.x;
      aF1+=q*wfq.y+k*wfk.y+v*wfv.y;
      aF2+=q*wfq.z+k*wfk.z+v*wfv.z;
      aF3+=q*wfq.w+k*wfk.w+v*wfv.w;
    }
  }
#pragma unroll
  for(int m=1;m<64;m<<=1){
    aI0+=__shfl_xor(aI0,m); aI1+=__shfl_xor(aI1,m);
    aI2+=__shfl_xor(aI2,m); aI3+=__shfl_xor(aI3,m);
    aF0+=__shfl_xor(aF0,m); aF1+=__shfl_xor(aF1,m);
    aF2+=__shfl_xor(aF2,m); aF3+=__shfl_xor(aF3,m);
  }
  if(l==0){
    const size_t o0=(size_t)(b*NH_+0)*S_+s;
    const size_t o1=(size_t)(b*NH_+1)*S_+s;
    const size_t o2=(size_t)(b*NH_+2)*S_+s;
    const size_t o3=(size_t)(b*NH_+3)*S_+s;
    igb[o0]=aI0+big[0]; igb[o1]=aI1+big[1];
    igb[o2]=aI2+big[2]; igb[o3]=aI3+big[3];
    logfb[o0]=logsigf(aF0+bfg[0]); logfb[o1]=logsigf(aF1+bfg[1]);
    logfb[o2]=logsigf(aF2+bfg[2]); logfb[o3]=logsigf(aF3+bfg[3]);
  }
}

// ---- K prep: split fp32 K into hi/lo bf16, MFMA B-fragment tile layout ----
__global__ __launch_bounds__(256) void kprep_k(const float* __restrict__ kb,
                                               unsigned short* __restrict__ khi,
                                               unsigned short* __restrict__ klo){
  const int blk=blockIdx.x;                 // 8 heads * 128 t-tiles
  const int head=blk>>7, tt=blk&127;
  const size_t obase=(size_t)blk*11*512;
  for(int slot=threadIdx.x; slot<704; slot+=256){
    const int dc=slot>>6, ll=slot&63, quad=ll>>4, lm=ll&15;
    const int tg=tt*16+lm, dbase=dc*32+quad*8;
    float v[8];
    if(dbase<336){
      load4(&kb[((size_t)head*S_+tg)*DH_+dbase],v);
      load4(&kb[((size_t)head*S_+tg)*DH_+dbase+4],v+4);
    } else { for(int j=0;j<8;j++) v[j]=0.f; }
    unsigned short hi8[8], lo8[8];
#pragma unroll
    for(int j=0;j<8;j++){
      hi8[j]=f2bf(v[j]);
      lo8[j]=f2bf(v[j]-bf2f(hi8[j]));
    }
    const size_t o=obase+(size_t)(dc*64+ll)*8;
    uint4 ph, pl;
    ph.x=(unsigned)hi8[0]|((unsigned)hi8[1]<<16); ph.y=(unsigned)hi8[2]|((unsigned)hi8[3]<<16);
    ph.z=(unsigned)hi8[4]|((unsigned)hi8[5]<<16); ph.w=(unsigned)hi8[6]|((unsigned)hi8[7]<<16);
    pl.x=(unsigned)lo8[0]|((unsigned)lo8[1]<<16); pl.y=(unsigned)lo8[2]|((unsigned)lo8[3]<<16);
    pl.z=(unsigned)lo8[4]|((unsigned)lo8[5]<<16); pl.w=(unsigned)lo8[6]|((unsigned)lo8[7]<<16);
    *reinterpret_cast<uint4*>(&khi[o])=ph;
    *reinterpret_cast<uint4*>(&klo[o])=pl;
  }
}

// ---- V prep: V^T bf16 in MFMA B-fragment tile layout; col 336 = ones ----
__global__ __launch_bounds__(256) void vprep_k(const float* __restrict__ vb,
                                               unsigned short* __restrict__ vTf){
  const int blk=blockIdx.x;                 // 8 heads * 64 t-chunks
  const int head=blk>>6, tc=blk&63;
  const size_t obase=(size_t)blk*22*512;
  for(int slot=threadIdx.x; slot<1408; slot+=256){
    const int ntg=slot>>6, ll=slot&63, quad=ll>>4, lm=ll&15;
    const int n=ntg*16+lm, t0=tc*32+quad*8;
    unsigned short h8[8];
#pragma unroll
    for(int j=0;j<8;j++){
      float val;
      if(n<336)       val=vb[((size_t)head*S_+t0+j)*DH_+n];
      else if(n==336) val=1.f;
      else            val=0.f;
      h8[j]=f2bf(val);
    }
    uint4 pk;
    pk.x=(unsigned)h8[0]|((unsigned)h8[1]<<16); pk.y=(unsigned)h8[2]|((unsigned)h8[3]<<16);
    pk.z=(unsigned)h8[4]|((unsigned)h8[5]<<16); pk.w=(unsigned)h8[6]|((unsigned)h8[7]<<16);
    *reinterpret_cast<uint4*>(&vTf[obase+(size_t)(ntg*64+ll)*8])=pk;
  }
}

// ---- parallel per-head scan ----
__global__ __launch_bounds__(256) void scan_k(const float* __restrict__ igb,
                                              const float* __restrict__ logfb,
                                              float* __restrict__ ab,float* __restrict__ Mb,
                                              float* __restrict__ mtb){
  const int head=blockIdx.x, t=threadIdx.x;
  __shared__ float sh[256];
  const float* lf=logfb+(size_t)head*S_;
  const float* ig=igb+(size_t)head*S_;
  float lc[8];
  float run=0.f;
#pragma unroll
  for(int i=0;i<8;i++){ run+=lf[t*8+i]; lc[i]=run; }
  sh[t]=run;
  for(int st=1;st<256;st<<=1){
    __syncthreads();
    const float v=(t>=st)?sh[t-st]:0.f;
    __syncthreads();
    sh[t]+=v;
  }
  __syncthreads();
  const float off=(t==0)?0.f:sh[t-1];
  __syncthreads();
  float av[8],mv[8],cv[8];
  float mrun=-1e30f;
#pragma unroll
  for(int i=0;i<8;i++){
    cv[i]=off+lc[i];
    av[i]=ig[t*8+i]-cv[i];
    mrun=fmaxf(mrun,av[i]);
    mv[i]=mrun;
  }
  sh[t]=mrun;
  for(int st=1;st<256;st<<=1){
    __syncthreads();
    const float v=(t>=st)?sh[t-st]:-1e30f;
    __syncthreads();
    sh[t]=fmaxf(sh[t],v);
  }
  __syncthreads();
  const float moff=(t==0)?-1e30f:sh[t-1];
#pragma unroll
  for(int i=0;i<8;i++){
    const float Mi=fmaxf(moff,mv[i]);
    const size_t j=(size_t)head*S_+t*8+i;
    ab[j]=av[i]; Mb[j]=Mi; mtb[j]=cv[i]+Mi;
  }
}

// ============================================================================
// mLSTM v12 — 512 threads: 8 waves x 16 rows = 128-row supertiles, paired
// p<->15-p, 4-way seg: 256 blocks x exactly 17 chunks. Same 66KB staged chunk
// now feeds 128 rows (2x arithmetic intensity per staged byte vs v9) and
// 2 waves/SIMD occupancy (TLP latency hiding). Per-wave state identical to
// v9 (184 VGPR, proven no-spill). Causally-dead waves skip compute.
// ============================================================================
__global__ __launch_bounds__(512,1) void mlstm6_k(
    const float* __restrict__ qb, const unsigned short* __restrict__ khi,
    const unsigned short* __restrict__ klo, const unsigned short* __restrict__ vTf,
    const float* __restrict__ ab, const float* __restrict__ Mb,
    float* __restrict__ part, float* __restrict__ rsum){
  const int bid=blockIdx.x;
  const int head=bid&7;                     // XCD pin: head h -> XCD h
  const int rest=bid>>3;                    // 0..31
  const int pairI=rest&7, seg=rest>>3;      // pair 0..7, seg 0..3
  const int t=threadIdx.x, w=t>>6, l=t&63, lm=l&15, quad=l>>4;

  // LDS: double-buffered chunk staging (66 frag-tiles of 512 shorts each)
  // layout per buffer: [0..21]=khi(2tt x 11dc), [22..43]=klo, [44..65]=vTf
  __shared__ short KV[2][66*512];
  __shared__ short Sc[8][16][40];

  const size_t hb=(size_t)head*S_;
  const float scale=0.05455447256f;         // 336^-0.5

  const int sbA=pairI, sbB=15-pairI;        // 128-row supertiles
  const int nA=pairI+1, nTot=17;            // uniform work across all blocks

  bf16x8 qh[11], ql[11];
  f32x4 accO[22];
  float Mr[4];
  int ws0=sbA*128+w*16;

  auto loadQ=[&](int ws0_){
    const float* qrow=qb+(hb+ws0_+lm)*DH_;
#pragma unroll
    for(int dc=0;dc<11;dc++){
      const int dbase=dc*32+quad*8;
      float v[8];
      if(dbase<336){ load4(qrow+dbase,v); load4(qrow+dbase+4,v+4); }
      else { for(int j=0;j<8;j++) v[j]=0.f; }
#pragma unroll
      for(int j=0;j<8;j++){
        const unsigned short h=f2bf(v[j]);
        qh[dc][j]=(short)h;
        ql[dc][j]=(short)f2bf(v[j]-bf2f(h));
      }
    }
#pragma unroll
    for(int r=0;r<4;r++) Mr[r]=Mb[hb+ws0_+quad*4+r];
#pragma unroll
    for(int n=0;n<22;n++) accO[n]={0.f,0.f,0.f,0.f};
  };

  // item i -> chunk index c (32-col chunks, stride-4 over seg)
  auto itemC=[&](int i)->int{
    return (i<nA)? (seg+4*i) : (seg+4*(i-nA));
  };

  // direct global->LDS DMA: per frag-tile, 64 lanes x 16B = 1024B. 8-9/wave.
  auto stage=[&](int buf,int c){
    const size_t kbase=(((size_t)head*128+(size_t)(2*c))*11)*512+(size_t)l*8;
    const size_t vbase=(((size_t)head*64+(size_t)c)*22)*512+(size_t)l*8;
#pragma unroll
    for(int j=0;j<9;j++){
      const int tr=w+8*j;
      if(tr<66){
        const unsigned short* src;
        if(tr<22)      src=&khi[kbase+(size_t)tr*512];
        else if(tr<44) src=&klo[kbase+(size_t)(tr-22)*512];
        else           src=&vTf[vbase+(size_t)(tr-44)*512];
        __builtin_amdgcn_global_load_lds(
          (const __attribute__((address_space(1))) unsigned int*)src,
          (__attribute__((address_space(3))) unsigned int*)&KV[buf][(size_t)tr*512],
          16,0,0);
      }
    }
  };

  auto compute=[&](int c,int buf){
    const int t0=c<<5;
    if(t0>ws0+15) return;                   // causally dead wave (uniform branch)
    const float al0=ab[hb+t0+lm];
    const float al1=ab[hb+t0+16+lm];
#pragma unroll
    for(int tt=0;tt<2;tt++){
      f32x4 a0={0,0,0,0}, a1={0,0,0,0}, a2={0,0,0,0};
#pragma unroll
      for(int dc=0;dc<11;dc++){
        const bf16x8 kh=*reinterpret_cast<const bf16x8*>(&KV[buf][(tt*11+dc)*512+l*8]);
        const bf16x8 kl=*reinterpret_cast<const bf16x8*>(&KV[buf][(22+tt*11+dc)*512+l*8]);
        a0=__builtin_amdgcn_mfma_f32_16x16x32_bf16(qh[dc],kh,a0,0,0,0);
        a1=__builtin_amdgcn_mfma_f32_16x16x32_bf16(ql[dc],kh,a1,0,0,0);
        a2=__builtin_amdgcn_mfma_f32_16x16x32_bf16(qh[dc],kl,a2,0,0,0);
      }
      const float al=(tt==0)?al0:al1;
      const int tg=t0+tt*16+lm;
#pragma unroll
      for(int r=0;r<4;r++){
        const int srow=quad*4+r;
        const float qk=a0[r]+a1[r]+a2[r];
        const float e=fminf(al-Mr[r],0.f);
        const float msk=(tg<=ws0+srow)?1.f:0.f;
        Sc[w][srow][tt*16+lm]=(short)f2bf(msk*(qk*scale*expf(e)));
      }
    }
    const bf16x8 scf=*reinterpret_cast<const bf16x8*>(&Sc[w][lm][quad*8]);
#pragma unroll
    for(int nt=0;nt<22;nt++){
      const bf16x8 vf=*reinterpret_cast<const bf16x8*>(&KV[buf][(44+nt)*512+l*8]);
      accO[nt]=__builtin_amdgcn_mfma_f32_16x16x32_bf16(scf,vf,accO[nt],0,0,0);
    }
  };

  auto epilogue=[&](){
    const size_t pbase=(size_t)head*2048+ws0;
#pragma unroll
    for(int nt=0;nt<22;nt++){
      const int col=nt*16+lm;
#pragma unroll
      for(int r=0;r<4;r++){
        const int srow=quad*4+r;
        const float val=accO[nt][r];
        if(col<336){ if(val!=0.f) atomicAdd(&part[(pbase+srow)*336+col],val); }
        else if(col==336){ if(val!=0.f) atomicAdd(&rsum[pbase+srow],val); }
      }
    }
  };

  loadQ(ws0);
  stage(0,itemC(0));
  __syncthreads();                          // drains vmcnt: buffer 0 ready
  int cur=0;
  for(int i=0;i<nTot;i++){
    if(i+1<nTot) stage(cur^1,itemC(i+1));   // DMA next chunk into back buffer
    compute(itemC(i),cur);
    if(i==nA-1){                            // tile switch: A done
      epilogue();
      ws0=sbB*128+w*16;
      loadQ(ws0);
    }
    __syncthreads();                        // drain DMA + cross-wave sync
    cur^=1;
  }
  epilogue();                               // tile B
}

// ============================================================================
// finalize: n-normalizer + per-head groupnorm + hout write (proven).
// ============================================================================
__global__ __launch_bounds__(256) void finalize_k(const float* __restrict__ part,
                                                  const float* __restrict__ rsum,
                                                  const float* __restrict__ mtb,
                                                  const float* __restrict__ lnw,
                                                  float* __restrict__ hout){
  const int sblk=blockIdx.x, head=blockIdx.y;
  const int bI=head>>2, nh=head&3;
  const int s0=sblk*32;
  const int t=threadIdx.x, row=t>>3, sub=t&7;
  __shared__ float red1[32][8], red2[32][8];
  __shared__ float mu_s[32], rs_s[32], inv_s[32];
  const size_t pbase=(size_t)head*2048+s0;
  const float* prow=part+(pbase+row)*336;
  float s1=0.f,s2=0.f;
  for(int c=sub;c<336;c+=8){ const float v=prow[c]; s1+=v; s2+=v*v; }
  red1[row][sub]=s1; red2[row][sub]=s2;
  __syncthreads();
  if(sub==0){
    float a1=0.f,a2=0.f;
#pragma unroll
    for(int j=0;j<8;j++){ a1+=red1[row][j]; a2+=red2[row][j]; }
    const float mt=mtb[(size_t)head*S_+s0+row];
    const float nn=fmaxf(fabsf(rsum[pbase+row]), expf(fminf(fmaxf(-mt,-60.f),60.f)));
    const float inv=1.f/(nn+1e-6f);
    const float mu=a1*inv/336.f;
    const float var=a2*inv*inv/336.f-mu*mu;
    inv_s[row]=inv; mu_s[row]=mu;
    rs_s[row]=rsqrtf(fmaxf(var,0.f)+1e-5f);
  }
  __syncthreads();
  const float inv=inv_s[row], mu=mu_s[row], rs=rs_s[row];
  float* orow=hout+((size_t)(bI*S_+s0+row))*H_+nh*DH_;
  for(int c=sub;c<336;c+=8)
    orow[c]=(prow[c]*inv-mu)*rs*lnw[nh*DH_+c];
}

// ---- h_state = (h_out + skip*act) * silu(z) ----
__global__ __launch_bounds__(256) void hstate_k(const float* __restrict__ hout,
                                                const float* __restrict__ act,
                                                const float* __restrict__ xin,
                                                const float* __restrict__ skip,
                                                float* __restrict__ hs){
  const int i=blockIdx.x*256+threadIdx.x;
  if(i>=(int)N_BSH) return;
  const int bs=i/H_, h=i-bs*H_;
  const float z=xin[(size_t)bs*H2_+H_+h];
  hs[(size_t)bs*H_+h]=(hout[(size_t)bs*H_+h]+skip[h]*act[(size_t)bs*H_+h])*siluf(z);
}

// ============================================================================
extern "C" void kernel_launch(void* const* d_in, const int* in_sizes, int n_in,
                              void* d_out, int out_size, void* d_ws, size_t ws_size,
                              hipStream_t stream){
  float* ws=(float*)d_ws;
  int* flag=(int*)ws;

  float* igb  = ws+O_IGB;
  float* logfb= ws+O_LOGF;
  float* ab   = ws+O_AB;
  float* Mbuf = ws+O_MB;
  float* mtb  = ws+O_MTB;
  float* f_ck = ws+O_CK;
  float* f_cb = ws+O_CB;
  float* f_wq = ws+O_WQ;
  float* f_wk = ws+O_WK;
  float* f_wv = ws+O_WV;
  float* f_wig= ws+O_WIG;
  float* f_big= ws+O_BIG;
  float* f_wfg= ws+O_WFG;
  float* f_bfg= ws+O_BFG;
  float* f_lnw= ws+O_LNW;
  float* f_skp= ws+O_SKP;
  float* xin  = ws+O_XIN;
  float* act  = ws+O_ACT;
  float* qb   = ws+O_QB;
  float* kb   = ws+O_KB;
  float* vb   = ws+O_VB;
  float* hout = ws+O_HOUT;
  float* hs   = qb;                            // alias: q dead after mlstm6_k

  unsigned short* xhi  =(unsigned short*)(ws+O_FX);   unsigned short* xlo  =xhi+N_X;
  unsigned short* wuphi=(unsigned short*)(ws+O_FWUP); unsigned short* wuplo=wuphi+N_WUP;
  unsigned short* wdnhi=(unsigned short*)(ws+O_FWDN); unsigned short* wdnlo=wdnhi+N_WDN;
  unsigned short* khi=(unsigned short*)(ws+O_FX);     // x/wup frags dead after up-gemm
  unsigned short* klo=khi+KSPLIT_SHORTS;
  unsigned short* vTf=(unsigned short*)kb;     // kb dead after gates+kprep
  unsigned short* hshi=(unsigned short*)kb;    // vTf dead after mlstm6_k
  unsigned short* hslo=hshi+N_BSH;
  float* partb=vb;                             // vb dead after vprep
  float* rsumb=igb;                            // igb dead after scan_k

  detect_k<<<1,256,0,stream>>>((const unsigned short*)d_in[0],flag);
  auto cvt=[&](int idx,float* dst,size_t n){
    convert_k<<<(int)((n+255)/256),256,0,stream>>>(d_in[idx],dst,(int)n,flag);
  };
  cvt(2,f_ck,N_CK);  cvt(3,f_cb,H_);
  cvt(4,f_wq,N_WH); cvt(5,f_wk,N_WH);   cvt(6,f_wv,N_WH);  cvt(7,f_wig,N_WG);
  cvt(8,f_big,4);   cvt(9,f_wfg,N_WG);  cvt(10,f_bfg,4);   cvt(11,f_lnw,H_);
  cvt(12,f_skp,H_);

  // up-GEMM: xin = x @ Wup  (M=4096,K=1024 kcn=32, N=2688)
  aprep_k<<<(256*32*64+255)/256,256,0,stream>>>(d_in[0],flag,32,1024,256*32*64,xhi,xlo);
  bprep_k<<<(168*32*64+255)/256,256,0,stream>>>(d_in[1],flag,32,2688,168*32*64,wuphi,wuplo);
  gemm_mfma_k<<<dim3(2688/64,4096/128),256,0,stream>>>(xhi,xlo,wuphi,wuplo,xin,nullptr,32,H2_);

  conv_act_k<<<(int)((N_BSH+255)/256),256,0,stream>>>(xin,f_ck,f_cb,act);
  qkv_k<<<(int)((N_BSH+255)/256),256,0,stream>>>(act,xin,f_wq,f_wk,f_wv,qb,kb,vb);
  // gates v2: one wave per (b,s) row, 4096 waves
  gates2_k<<<(BS_*64+255)/256,256,0,stream>>>(qb,kb,vb,f_wig,f_big,f_wfg,f_bfg,igb,logfb);
  kprep_k<<<8*128,256,0,stream>>>(kb,khi,klo);
  vprep_k<<<8*64,256,0,stream>>>(vb,vTf);
  // wdn frags (independent; region untouched by khi/klo)
  bprep_k<<<(64*42*64+255)/256,256,0,stream>>>(d_in[13],flag,42,1024,64*42*64,wdnhi,wdnlo);
  scan_k<<<B_*NH_,256,0,stream>>>(igb,logfb,ab,Mbuf,mtb);
  hipMemsetAsync(partb,0,N_BSH*sizeof(float),stream);
  hipMemsetAsync(rsumb,0,(size_t)NG_*sizeof(float),stream);
  // mLSTM v12: 256 blocks x 512 thr = 8 heads x 8 pairs x 4 seg; 17 chunks each
  mlstm6_k<<<256,512,0,stream>>>(qb,khi,klo,vTf,ab,Mbuf,partb,rsumb);
  finalize_k<<<dim3(S_/32,B_*NH_),256,0,stream>>>(partb,rsumb,mtb,f_lnw,hout);
  hstate_k<<<(int)((N_BSH+255)/256),256,0,stream>>>(hout,act,xin,f_skp,hs);
  // down-GEMM: out = hs @ Wdn  (M=4096,K=1344 kcn=42, N=1024), direct to d_out
  aprep_k<<<(256*42*64+255)/256,256,0,stream>>>(hs,nullptr,42,1344,256*42*64,hshi,hslo);
  gemm_mfma_k<<<dim3(1024/64,4096/128),256,0,stream>>>(hshi,hslo,wdnhi,wdnlo,d_out,flag,42,E_);
}

// Round 7
// 503.386 us; speedup vs baseline: 1.5155x; 1.0428x over previous
//
#include <hip/hip_runtime.h>
#include <cmath>

#define DI __device__ __forceinline__

constexpr int B_=2, S_=2048, E_=1024, H_=1344, NH_=4, DH_=336;
constexpr int BS_=B_*S_, H2_=2*H_;
constexpr int NG_=B_*NH_*S_;   // 16384

constexpr size_t N_X=(size_t)BS_*E_;
constexpr size_t N_WUP=(size_t)E_*H2_;
constexpr size_t N_WDN=(size_t)H_*E_;
constexpr size_t N_BSH=(size_t)BS_*H_;
constexpr size_t N_BSH2=(size_t)BS_*H2_;
constexpr size_t N_WH=5376, N_WG=16128, N_CK=4*H_;

// ---- ws layout (floats); identical to prior passing rounds ----
constexpr size_t O_IGB = 64;
constexpr size_t O_LOGF= O_IGB + NG_;
constexpr size_t O_AB  = O_LOGF+ NG_;
constexpr size_t O_MB  = O_AB  + NG_;
constexpr size_t O_MTB = O_MB  + NG_;
constexpr size_t O_CK  = O_MTB + NG_;
constexpr size_t O_CB  = O_CK  + N_CK;
constexpr size_t O_WQ  = O_CB  + H_;
constexpr size_t O_WK  = O_WQ  + N_WH;
constexpr size_t O_WV  = O_WK  + N_WH;
constexpr size_t O_WIG = O_WV  + N_WH;
constexpr size_t O_BIG = O_WIG + N_WG;
constexpr size_t O_WFG = O_BIG + 16;
constexpr size_t O_BFG = O_WFG + N_WG;
constexpr size_t O_LNW = O_BFG + 16;
constexpr size_t O_SKP = O_LNW + H_;
constexpr size_t O_FX  = O_SKP + H_;
constexpr size_t O_FWUP= O_FX  + N_X;
constexpr size_t O_FWDN= O_FWUP+ N_WUP;
constexpr size_t O_XIN = O_FWDN+ N_WDN;
constexpr size_t O_ACT = O_XIN + N_BSH2;
constexpr size_t O_QB  = O_ACT + N_BSH;
constexpr size_t O_KB  = O_QB  + N_BSH;
constexpr size_t O_VB  = O_KB  + N_BSH;
constexpr size_t O_HOUT= O_VB  + N_BSH;

// khi/klo: [head][tile=t/16][dc=0..10][l][8] bf16 (B-frag 16x16x32)
constexpr size_t KSPLIT_SHORTS=(size_t)8*128*11*64*8;  // 5,767,168
// vTf: [head][tc=t/32][ntg=0..21][l][8] bf16; n==336 -> 1.0 (rowsum), n>336 -> 0
constexpr size_t VT_SHORTS=(size_t)8*64*22*64*8;       // 5,767,168

typedef __attribute__((ext_vector_type(8))) short bf16x8;
typedef __attribute__((ext_vector_type(4))) float f32x4;

DI float bf2f(unsigned int u){union{unsigned int i;float f;}v;v.i=(u&0xffffu)<<16;return v.f;}
DI unsigned short f2bf(float f){union{float f;unsigned int i;}v;v.f=f;unsigned int x=v.i;
  return (unsigned short)((x+0x7fffu+((x>>16)&1u))>>16);}
DI float siluf(float x){return x/(1.f+expf(-x));}
DI float logsigf(float x){return (x>=0.f)?-log1pf(expf(-x)):x-log1pf(expf(x));}
DI void load4(const float* p, float* d){float4 v=*reinterpret_cast<const float4*>(p);
  d[0]=v.x;d[1]=v.y;d[2]=v.z;d[3]=v.w;}

// ---- dtype detect (fp32 proven; keep the guard) ----
__global__ __launch_bounds__(256) void detect_k(const unsigned short* __restrict__ xraw,
                                                int* __restrict__ flag){
  __shared__ int cnt_s;
  if(threadIdx.x==0) cnt_s=0;
  __syncthreads();
  int c=0;
  for(int i=threadIdx.x;i<2048;i+=256){
    const unsigned e=(xraw[i]>>7)&0xFFu;
    if(e>=0x90u) c++;
  }
  atomicAdd(&cnt_s,c);
  __syncthreads();
  if(threadIdx.x==0) *flag=(cnt_s>16)?0:1;
}

// ---- fused weight conversion: all 11 small tensors in one launch ----
constexpr int CV0=5376, CV1=CV0+1344, CV2=CV1+5376, CV3=CV2+5376, CV4=CV3+5376,
              CV5=CV4+16128, CV6=CV5+4, CV7=CV6+16128, CV8=CV7+4,
              CV9=CV8+1344, CVT=CV9+1344;     // 57800 total
__global__ __launch_bounds__(256) void convall_k(
    const void* s0,const void* s1,const void* s2,const void* s3,const void* s4,
    const void* s5,const void* s6,const void* s7,const void* s8,const void* s9,
    const void* s10, float* __restrict__ ws, const int* __restrict__ flag){
  const int i=blockIdx.x*256+threadIdx.x;
  if(i>=CVT) return;
  const void* src; int off; size_t dst;
  if(i<CV0){src=s0; off=i;      dst=O_CK +off;}
  else if(i<CV1){src=s1; off=i-CV0; dst=O_CB +off;}
  else if(i<CV2){src=s2; off=i-CV1; dst=O_WQ +off;}
  else if(i<CV3){src=s3; off=i-CV2; dst=O_WK +off;}
  else if(i<CV4){src=s4; off=i-CV3; dst=O_WV +off;}
  else if(i<CV5){src=s5; off=i-CV4; dst=O_WIG+off;}
  else if(i<CV6){src=s6; off=i-CV5; dst=O_BIG+off;}
  else if(i<CV7){src=s7; off=i-CV6; dst=O_WFG+off;}
  else if(i<CV8){src=s8; off=i-CV7; dst=O_BFG+off;}
  else if(i<CV9){src=s9; off=i-CV8; dst=O_LNW+off;}
  else          {src=s10;off=i-CV9; dst=O_SKP+off;}
  ws[dst]=(*flag)?bf2f(((const unsigned short*)src)[off])
                 :((const float*)src)[off];
}

// ============================================================================
// A-fragment prep
// ============================================================================
__global__ __launch_bounds__(256) void aprep_k(const void* __restrict__ src,
                                               const int* __restrict__ flag,
                                               int kcn,int ldk,int total,
                                               unsigned short* __restrict__ hi,
                                               unsigned short* __restrict__ lo){
  const int slot=blockIdx.x*256+threadIdx.x;
  if(slot>=total) return;
  const int l=slot&63, rest=slot>>6;
  const int kc=rest%kcn, mt=rest/kcn;
  const int row=mt*16+(l&15), k0=kc*32+(l>>4)*8;
  const int fl=flag?*flag:0;
  float v[8];
  if(fl){
    const unsigned short* s=(const unsigned short*)src+(size_t)row*ldk+k0;
    const uint4 u=*reinterpret_cast<const uint4*>(s);
    v[0]=bf2f(u.x);v[1]=bf2f(u.x>>16);v[2]=bf2f(u.y);v[3]=bf2f(u.y>>16);
    v[4]=bf2f(u.z);v[5]=bf2f(u.z>>16);v[6]=bf2f(u.w);v[7]=bf2f(u.w>>16);
  }else{
    const float* s=(const float*)src+(size_t)row*ldk+k0;
    load4(s,v); load4(s+4,v+4);
  }
  unsigned short h8[8], l8[8];
#pragma unroll
  for(int j=0;j<8;j++){ h8[j]=f2bf(v[j]); l8[j]=f2bf(v[j]-bf2f(h8[j])); }
  uint4 ph,pl;
  ph.x=(unsigned)h8[0]|((unsigned)h8[1]<<16); ph.y=(unsigned)h8[2]|((unsigned)h8[3]<<16);
  ph.z=(unsigned)h8[4]|((unsigned)h8[5]<<16); ph.w=(unsigned)h8[6]|((unsigned)h8[7]<<16);
  pl.x=(unsigned)l8[0]|((unsigned)l8[1]<<16); pl.y=(unsigned)l8[2]|((unsigned)l8[3]<<16);
  pl.z=(unsigned)l8[4]|((unsigned)l8[5]<<16); pl.w=(unsigned)l8[6]|((unsigned)l8[7]<<16);
  *reinterpret_cast<uint4*>(&hi[(size_t)slot*8])=ph;
  *reinterpret_cast<uint4*>(&lo[(size_t)slot*8])=pl;
}

// ============================================================================
// B-fragment prep
// ============================================================================
__global__ __launch_bounds__(256) void bprep_k(const void* __restrict__ src,
                                               const int* __restrict__ flag,
                                               int kcn,int ldn,int total,
                                               unsigned short* __restrict__ hi,
                                               unsigned short* __restrict__ lo){
  const int slot=blockIdx.x*256+threadIdx.x;
  if(slot>=total) return;
  const int l=slot&63, rest=slot>>6;
  const int kc=rest%kcn, nt=rest/kcn;
  const int col=nt*16+(l&15), row0=kc*32+(l>>4)*8;
  const int fl=flag?*flag:0;
  float v[8];
  if(fl){
    const unsigned short* s=(const unsigned short*)src;
#pragma unroll
    for(int j=0;j<8;j++) v[j]=bf2f(s[(size_t)(row0+j)*ldn+col]);
  }else{
    const float* s=(const float*)src;
#pragma unroll
    for(int j=0;j<8;j++) v[j]=s[(size_t)(row0+j)*ldn+col];
  }
  unsigned short h8[8], l8[8];
#pragma unroll
  for(int j=0;j<8;j++){ h8[j]=f2bf(v[j]); l8[j]=f2bf(v[j]-bf2f(h8[j])); }
  uint4 ph,pl;
  ph.x=(unsigned)h8[0]|((unsigned)h8[1]<<16); ph.y=(unsigned)h8[2]|((unsigned)h8[3]<<16);
  ph.z=(unsigned)h8[4]|((unsigned)h8[5]<<16); ph.w=(unsigned)h8[6]|((unsigned)h8[7]<<16);
  pl.x=(unsigned)l8[0]|((unsigned)l8[1]<<16); pl.y=(unsigned)l8[2]|((unsigned)l8[3]<<16);
  pl.z=(unsigned)l8[4]|((unsigned)l8[5]<<16); pl.w=(unsigned)l8[6]|((unsigned)l8[7]<<16);
  *reinterpret_cast<uint4*>(&hi[(size_t)slot*8])=ph;
  *reinterpret_cast<uint4*>(&lo[(size_t)slot*8])=pl;
}

// ============================================================================
// GEMM v2: 128x128 tile, 4 waves, global_load_lds double-buffered staging
// (mlstm6-proven pipeline). Per kc: 32 frag-tiles (8Ahi,8Alo,8Bhi,8Blo) DMA'd
// to LDS; each wave: 2 mt x 8 nt x 3-chain = 48 MFMA from LDS frags.
// B traffic /4 vs frag-direct; loads never transit VGPRs.
// ============================================================================
__global__ __launch_bounds__(256) void gemm2_k(
    const unsigned short* __restrict__ Ahi, const unsigned short* __restrict__ Alo,
    const unsigned short* __restrict__ Bhi, const unsigned short* __restrict__ Blo,
    void* __restrict__ C, const int* __restrict__ flag, int kcn, int ldc){
  const int t=threadIdx.x, w=t>>6, l=t&63, lm=l&15, quad=l>>4;
  const int bn=blockIdx.x*128, bm=blockIdx.y*128;
  const int mtg0=bm>>4, ntg0=bn>>4;

  __shared__ short TT[2][32*512];           // [0-7]Ahi [8-15]Alo [16-23]Bhi [24-31]Blo

  f32x4 acc[2][8];
#pragma unroll
  for(int g=0;g<2;g++)
#pragma unroll
    for(int nt=0;nt<8;nt++) acc[g][nt]={0.f,0.f,0.f,0.f};

  auto stage=[&](int buf,int kc){
#pragma unroll
    for(int j=0;j<8;j++){
      const int tr=w*8+j;
      const unsigned short* src;
      if(tr<8)       src=&Ahi[((size_t)(mtg0+tr   )*kcn+kc)*512+(size_t)l*8];
      else if(tr<16) src=&Alo[((size_t)(mtg0+tr-8 )*kcn+kc)*512+(size_t)l*8];
      else if(tr<24) src=&Bhi[((size_t)(ntg0+tr-16)*kcn+kc)*512+(size_t)l*8];
      else           src=&Blo[((size_t)(ntg0+tr-24)*kcn+kc)*512+(size_t)l*8];
      __builtin_amdgcn_global_load_lds(
        (const __attribute__((address_space(1))) unsigned int*)src,
        (__attribute__((address_space(3))) unsigned int*)&TT[buf][tr*512],
        16,0,0);
    }
  };

  auto compute=[&](int buf){
    const short* Tb=&TT[buf][0];
    const bf16x8 ah0=*reinterpret_cast<const bf16x8*>(&Tb[(2*w  )*512+l*8]);
    const bf16x8 ah1=*reinterpret_cast<const bf16x8*>(&Tb[(2*w+1)*512+l*8]);
    const bf16x8 al0=*reinterpret_cast<const bf16x8*>(&Tb[(8+2*w  )*512+l*8]);
    const bf16x8 al1=*reinterpret_cast<const bf16x8*>(&Tb[(8+2*w+1)*512+l*8]);
#pragma unroll
    for(int nt=0;nt<8;nt++){
      const bf16x8 bh=*reinterpret_cast<const bf16x8*>(&Tb[(16+nt)*512+l*8]);
      const bf16x8 bl=*reinterpret_cast<const bf16x8*>(&Tb[(24+nt)*512+l*8]);
      acc[0][nt]=__builtin_amdgcn_mfma_f32_16x16x32_bf16(ah0,bh,acc[0][nt],0,0,0);
      acc[0][nt]=__builtin_amdgcn_mfma_f32_16x16x32_bf16(al0,bh,acc[0][nt],0,0,0);
      acc[0][nt]=__builtin_amdgcn_mfma_f32_16x16x32_bf16(ah0,bl,acc[0][nt],0,0,0);
      acc[1][nt]=__builtin_amdgcn_mfma_f32_16x16x32_bf16(ah1,bh,acc[1][nt],0,0,0);
      acc[1][nt]=__builtin_amdgcn_mfma_f32_16x16x32_bf16(al1,bh,acc[1][nt],0,0,0);
      acc[1][nt]=__builtin_amdgcn_mfma_f32_16x16x32_bf16(ah1,bl,acc[1][nt],0,0,0);
    }
  };

  stage(0,0);
  __syncthreads();
  for(int kc=0;kc<kcn;kc++){
    const int cur=kc&1;
    if(kc+1<kcn) stage(cur^1,kc+1);
    compute(cur);
    __syncthreads();
  }

  const int bf=flag?*flag:0;
#pragma unroll
  for(int g=0;g<2;g++)
#pragma unroll
    for(int nt=0;nt<8;nt++)
#pragma unroll
      for(int r=0;r<4;r++){
        const size_t idx=(size_t)(bm+(2*w+g)*16+quad*4+r)*ldc+bn+nt*16+lm;
        if(bf) ((unsigned short*)C)[idx]=f2bf(acc[g][nt][r]);
        else   ((float*)C)[idx]=acc[g][nt][r];
      }
}

// ---- causal depthwise conv(K=4)+bias -> SiLU ----
__global__ __launch_bounds__(256) void conv_act_k(const float* __restrict__ xin,
                                                  const float* __restrict__ ck,
                                                  const float* __restrict__ cb,
                                                  float* __restrict__ act){
  const int i=blockIdx.x*256+threadIdx.x;
  if(i>=(int)N_BSH) return;
  const int bs=i/H_, h=i-bs*H_;
  const int b=bs/S_, s=bs-b*S_;
  float xc=cb[h];
#pragma unroll
  for(int w=0;w<4;w++){
    const int sr=s-3+w;
    if(sr>=0) xc+=xin[(size_t)(b*S_+sr)*H2_+h]*ck[w*H_+h];
  }
  act[(size_t)bs*H_+h]=siluf(xc);
}

// ---- headwise q/k/v ----
__global__ __launch_bounds__(256) void qkv_k(const float* __restrict__ act,
                                             const float* __restrict__ xin,
                                             const float* __restrict__ Wq,
                                             const float* __restrict__ Wk,
                                             const float* __restrict__ Wv,
                                             float* __restrict__ qb,float* __restrict__ kb,
                                             float* __restrict__ vb){
  const int i=blockIdx.x*256+threadIdx.x;
  if(i>=(int)N_BSH) return;
  const int bs=i/H_, h=i-bs*H_;
  const int b=bs/S_, s=bs-b*S_;
  const int ph=h>>2, o=h&3, base=ph*4;
  float q=0.f,k=0.f,v=0.f;
#pragma unroll
  for(int d=0;d<4;d++){
    const float a=act[(size_t)bs*H_+base+d];
    const float x=xin[(size_t)bs*H2_+base+d];
    q+=a*Wq[ph*16+d*4+o];
    k+=a*Wk[ph*16+d*4+o];
    v+=x*Wv[ph*16+d*4+o];
  }
  const int nh=h/DH_, dh=h-nh*DH_;
  const size_t off=((size_t)(b*NH_+nh)*S_+s)*DH_+dh;
  qb[off]=q; kb[off]=k; vb[off]=v;
}

// ============================================================================
// gates v2 — one wave per (b,s) row (passing, fast)
// ============================================================================
__global__ __launch_bounds__(256) void gates2_k(const float* __restrict__ qb,
                                                const float* __restrict__ kb,
                                                const float* __restrict__ vb,
                                                const float* __restrict__ Wig,
                                                const float* __restrict__ big,
                                                const float* __restrict__ Wfg,
                                                const float* __restrict__ bfg,
                                                float* __restrict__ igb,
                                                float* __restrict__ logfb){
  const int wid=(blockIdx.x*256+threadIdx.x)>>6;   // row = (b,s), 4096 waves
  const int l=threadIdx.x&63;
  if(wid>=BS_) return;
  const int b=wid>>11, s=wid&2047;
  float aI0=0.f,aI1=0.f,aI2=0.f,aI3=0.f;
  float aF0=0.f,aF1=0.f,aF2=0.f,aF3=0.f;
  for(int nh=0;nh<NH_;nh++){
    const size_t rb=((size_t)(b*NH_+nh)*S_+s)*DH_;
    const int hb=nh*DH_;
    for(int dh=l;dh<DH_;dh+=64){
      const int h=hb+dh;
      const float q=qb[rb+dh], k=kb[rb+dh], v=vb[rb+dh];
      const float4 wiq=*reinterpret_cast<const float4*>(&Wig[(size_t)h*4]);
      const float4 wik=*reinterpret_cast<const float4*>(&Wig[(size_t)(H_+h)*4]);
      const float4 wiv=*reinterpret_cast<const float4*>(&Wig[(size_t)(2*H_+h)*4]);
      const float4 wfq=*reinterpret_cast<const float4*>(&Wfg[(size_t)h*4]);
      const float4 wfk=*reinterpret_cast<const float4*>(&Wfg[(size_t)(H_+h)*4]);
      const float4 wfv=*reinterpret_cast<const float4*>(&Wfg[(size_t)(2*H_+h)*4]);
      aI0+=q*wiq.x+k*wik.x+v*wiv.x;
      aI1+=q*wiq.y+k*wik.y+v*wiv.y;
      aI2+=q*wiq.z+k*wik.z+v*wiv.z;
      aI3+=q*wiq.w+k*wik.w+v*wiv.w;
      aF0+=q*wfq.x+k*wfk.x+v*wfv.x;
      aF1+=q*wfq.y+k*wfk.y+v*wfv.y;
      aF2+=q*wfq.z+k*wfk.z+v*wfv.z;
      aF3+=q*wfq.w+k*wfk.w+v*wfv.w;
    }
  }
#pragma unroll
  for(int m=1;m<64;m<<=1){
    aI0+=__shfl_xor(aI0,m); aI1+=__shfl_xor(aI1,m);
    aI2+=__shfl_xor(aI2,m); aI3+=__shfl_xor(aI3,m);
    aF0+=__shfl_xor(aF0,m); aF1+=__shfl_xor(aF1,m);
    aF2+=__shfl_xor(aF2,m); aF3+=__shfl_xor(aF3,m);
  }
  if(l==0){
    const size_t o0=(size_t)(b*NH_+0)*S_+s;
    const size_t o1=(size_t)(b*NH_+1)*S_+s;
    const size_t o2=(size_t)(b*NH_+2)*S_+s;
    const size_t o3=(size_t)(b*NH_+3)*S_+s;
    igb[o0]=aI0+big[0]; igb[o1]=aI1+big[1];
    igb[o2]=aI2+big[2]; igb[o3]=aI3+big[3];
    logfb[o0]=logsigf(aF0+bfg[0]); logfb[o1]=logsigf(aF1+bfg[1]);
    logfb[o2]=logsigf(aF2+bfg[2]); logfb[o3]=logsigf(aF3+bfg[3]);
  }
}

// ---- K prep: split fp32 K into hi/lo bf16, MFMA B-fragment tile layout ----
__global__ __launch_bounds__(256) void kprep_k(const float* __restrict__ kb,
                                               unsigned short* __restrict__ khi,
                                               unsigned short* __restrict__ klo){
  const int blk=blockIdx.x;                 // 8 heads * 128 t-tiles
  const int head=blk>>7, tt=blk&127;
  const size_t obase=(size_t)blk*11*512;
  for(int slot=threadIdx.x; slot<704; slot+=256){
    const int dc=slot>>6, ll=slot&63, quad=ll>>4, lm=ll&15;
    const int tg=tt*16+lm, dbase=dc*32+quad*8;
    float v[8];
    if(dbase<336){
      load4(&kb[((size_t)head*S_+tg)*DH_+dbase],v);
      load4(&kb[((size_t)head*S_+tg)*DH_+dbase+4],v+4);
    } else { for(int j=0;j<8;j++) v[j]=0.f; }
    unsigned short hi8[8], lo8[8];
#pragma unroll
    for(int j=0;j<8;j++){
      hi8[j]=f2bf(v[j]);
      lo8[j]=f2bf(v[j]-bf2f(hi8[j]));
    }
    const size_t o=obase+(size_t)(dc*64+ll)*8;
    uint4 ph, pl;
    ph.x=(unsigned)hi8[0]|((unsigned)hi8[1]<<16); ph.y=(unsigned)hi8[2]|((unsigned)hi8[3]<<16);
    ph.z=(unsigned)hi8[4]|((unsigned)hi8[5]<<16); ph.w=(unsigned)hi8[6]|((unsigned)hi8[7]<<16);
    pl.x=(unsigned)lo8[0]|((unsigned)lo8[1]<<16); pl.y=(unsigned)lo8[2]|((unsigned)lo8[3]<<16);
    pl.z=(unsigned)lo8[4]|((unsigned)lo8[5]<<16); pl.w=(unsigned)lo8[6]|((unsigned)lo8[7]<<16);
    *reinterpret_cast<uint4*>(&khi[o])=ph;
    *reinterpret_cast<uint4*>(&klo[o])=pl;
  }
}

// ---- V prep: V^T bf16 in MFMA B-fragment tile layout; col 336 = ones ----
__global__ __launch_bounds__(256) void vprep_k(const float* __restrict__ vb,
                                               unsigned short* __restrict__ vTf){
  const int blk=blockIdx.x;                 // 8 heads * 64 t-chunks
  const int head=blk>>6, tc=blk&63;
  const size_t obase=(size_t)blk*22*512;
  for(int slot=threadIdx.x; slot<1408; slot+=256){
    const int ntg=slot>>6, ll=slot&63, quad=ll>>4, lm=ll&15;
    const int n=ntg*16+lm, t0=tc*32+quad*8;
    unsigned short h8[8];
#pragma unroll
    for(int j=0;j<8;j++){
      float val;
      if(n<336)       val=vb[((size_t)head*S_+t0+j)*DH_+n];
      else if(n==336) val=1.f;
      else            val=0.f;
      h8[j]=f2bf(val);
    }
    uint4 pk;
    pk.x=(unsigned)h8[0]|((unsigned)h8[1]<<16); pk.y=(unsigned)h8[2]|((unsigned)h8[3]<<16);
    pk.z=(unsigned)h8[4]|((unsigned)h8[5]<<16); pk.w=(unsigned)h8[6]|((unsigned)h8[7]<<16);
    *reinterpret_cast<uint4*>(&vTf[obase+(size_t)(ntg*64+ll)*8])=pk;
  }
}

// ---- parallel per-head scan ----
__global__ __launch_bounds__(256) void scan_k(const float* __restrict__ igb,
                                              const float* __restrict__ logfb,
                                              float* __restrict__ ab,float* __restrict__ Mb,
                                              float* __restrict__ mtb){
  const int head=blockIdx.x, t=threadIdx.x;
  __shared__ float sh[256];
  const float* lf=logfb+(size_t)head*S_;
  const float* ig=igb+(size_t)head*S_;
  float lc[8];
  float run=0.f;
#pragma unroll
  for(int i=0;i<8;i++){ run+=lf[t*8+i]; lc[i]=run; }
  sh[t]=run;
  for(int st=1;st<256;st<<=1){
    __syncthreads();
    const float v=(t>=st)?sh[t-st]:0.f;
    __syncthreads();
    sh[t]+=v;
  }
  __syncthreads();
  const float off=(t==0)?0.f:sh[t-1];
  __syncthreads();
  float av[8],mv[8],cv[8];
  float mrun=-1e30f;
#pragma unroll
  for(int i=0;i<8;i++){
    cv[i]=off+lc[i];
    av[i]=ig[t*8+i]-cv[i];
    mrun=fmaxf(mrun,av[i]);
    mv[i]=mrun;
  }
  sh[t]=mrun;
  for(int st=1;st<256;st<<=1){
    __syncthreads();
    const float v=(t>=st)?sh[t-st]:-1e30f;
    __syncthreads();
    sh[t]=fmaxf(sh[t],v);
  }
  __syncthreads();
  const float moff=(t==0)?-1e30f:sh[t-1];
#pragma unroll
  for(int i=0;i<8;i++){
    const float Mi=fmaxf(moff,mv[i]);
    const size_t j=(size_t)head*S_+t*8+i;
    ab[j]=av[i]; Mb[j]=Mi; mtb[j]=cv[i]+Mi;
  }
}

// ============================================================================
// mLSTM v12 — 512 threads: 8 waves x 16 rows = 128-row supertiles (passing).
// ============================================================================
__global__ __launch_bounds__(512,1) void mlstm6_k(
    const float* __restrict__ qb, const unsigned short* __restrict__ khi,
    const unsigned short* __restrict__ klo, const unsigned short* __restrict__ vTf,
    const float* __restrict__ ab, const float* __restrict__ Mb,
    float* __restrict__ part, float* __restrict__ rsum){
  const int bid=blockIdx.x;
  const int head=bid&7;                     // XCD pin: head h -> XCD h
  const int rest=bid>>3;                    // 0..31
  const int pairI=rest&7, seg=rest>>3;      // pair 0..7, seg 0..3
  const int t=threadIdx.x, w=t>>6, l=t&63, lm=l&15, quad=l>>4;

  __shared__ short KV[2][66*512];
  __shared__ short Sc[8][16][40];

  const size_t hb=(size_t)head*S_;
  const float scale=0.05455447256f;         // 336^-0.5

  const int sbA=pairI, sbB=15-pairI;        // 128-row supertiles
  const int nA=pairI+1, nTot=17;            // uniform work across all blocks

  bf16x8 qh[11], ql[11];
  f32x4 accO[22];
  float Mr[4];
  int ws0=sbA*128+w*16;

  auto loadQ=[&](int ws0_){
    const float* qrow=qb+(hb+ws0_+lm)*DH_;
#pragma unroll
    for(int dc=0;dc<11;dc++){
      const int dbase=dc*32+quad*8;
      float v[8];
      if(dbase<336){ load4(qrow+dbase,v); load4(qrow+dbase+4,v+4); }
      else { for(int j=0;j<8;j++) v[j]=0.f; }
#pragma unroll
      for(int j=0;j<8;j++){
        const unsigned short h=f2bf(v[j]);
        qh[dc][j]=(short)h;
        ql[dc][j]=(short)f2bf(v[j]-bf2f(h));
      }
    }
#pragma unroll
    for(int r=0;r<4;r++) Mr[r]=Mb[hb+ws0_+quad*4+r];
#pragma unroll
    for(int n=0;n<22;n++) accO[n]={0.f,0.f,0.f,0.f};
  };

  auto itemC=[&](int i)->int{
    return (i<nA)? (seg+4*i) : (seg+4*(i-nA));
  };

  auto stage=[&](int buf,int c){
    const size_t kbase=(((size_t)head*128+(size_t)(2*c))*11)*512+(size_t)l*8;
    const size_t vbase=(((size_t)head*64+(size_t)c)*22)*512+(size_t)l*8;
#pragma unroll
    for(int j=0;j<9;j++){
      const int tr=w+8*j;
      if(tr<66){
        const unsigned short* src;
        if(tr<22)      src=&khi[kbase+(size_t)tr*512];
        else if(tr<44) src=&klo[kbase+(size_t)(tr-22)*512];
        else           src=&vTf[vbase+(size_t)(tr-44)*512];
        __builtin_amdgcn_global_load_lds(
          (const __attribute__((address_space(1))) unsigned int*)src,
          (__attribute__((address_space(3))) unsigned int*)&KV[buf][(size_t)tr*512],
          16,0,0);
      }
    }
  };

  auto compute=[&](int c,int buf){
    const int t0=c<<5;
    if(t0>ws0+15) return;                   // causally dead wave (uniform branch)
    const float al0=ab[hb+t0+lm];
    const float al1=ab[hb+t0+16+lm];
#pragma unroll
    for(int tt=0;tt<2;tt++){
      f32x4 a0={0,0,0,0}, a1={0,0,0,0}, a2={0,0,0,0};
#pragma unroll
      for(int dc=0;dc<11;dc++){
        const bf16x8 kh=*reinterpret_cast<const bf16x8*>(&KV[buf][(tt*11+dc)*512+l*8]);
        const bf16x8 kl=*reinterpret_cast<const bf16x8*>(&KV[buf][(22+tt*11+dc)*512+l*8]);
        a0=__builtin_amdgcn_mfma_f32_16x16x32_bf16(qh[dc],kh,a0,0,0,0);
        a1=__builtin_amdgcn_mfma_f32_16x16x32_bf16(ql[dc],kh,a1,0,0,0);
        a2=__builtin_amdgcn_mfma_f32_16x16x32_bf16(qh[dc],kl,a2,0,0,0);
      }
      const float al=(tt==0)?al0:al1;
      const int tg=t0+tt*16+lm;
#pragma unroll
      for(int r=0;r<4;r++){
        const int srow=quad*4+r;
        const float qk=a0[r]+a1[r]+a2[r];
        const float e=fminf(al-Mr[r],0.f);
        const float msk=(tg<=ws0+srow)?1.f:0.f;
        Sc[w][srow][tt*16+lm]=(short)f2bf(msk*(qk*scale*expf(e)));
      }
    }
    const bf16x8 scf=*reinterpret_cast<const bf16x8*>(&Sc[w][lm][quad*8]);
#pragma unroll
    for(int nt=0;nt<22;nt++){
      const bf16x8 vf=*reinterpret_cast<const bf16x8*>(&KV[buf][(44+nt)*512+l*8]);
      accO[nt]=__builtin_amdgcn_mfma_f32_16x16x32_bf16(scf,vf,accO[nt],0,0,0);
    }
  };

  auto epilogue=[&](){
    const size_t pbase=(size_t)head*2048+ws0;
#pragma unroll
    for(int nt=0;nt<22;nt++){
      const int col=nt*16+lm;
#pragma unroll
      for(int r=0;r<4;r++){
        const int srow=quad*4+r;
        const float val=accO[nt][r];
        if(col<336){ if(val!=0.f) atomicAdd(&part[(pbase+srow)*336+col],val); }
        else if(col==336){ if(val!=0.f) atomicAdd(&rsum[pbase+srow],val); }
      }
    }
  };

  loadQ(ws0);
  stage(0,itemC(0));
  __syncthreads();                          // drains vmcnt: buffer 0 ready
  int cur=0;
  for(int i=0;i<nTot;i++){
    if(i+1<nTot) stage(cur^1,itemC(i+1));   // DMA next chunk into back buffer
    compute(itemC(i),cur);
    if(i==nA-1){                            // tile switch: A done
      epilogue();
      ws0=sbB*128+w*16;
      loadQ(ws0);
    }
    __syncthreads();                        // drain DMA + cross-wave sync
    cur^=1;
  }
  epilogue();                               // tile B
}

// ============================================================================
// finalize: n-normalizer + per-head groupnorm + hout write (proven).
// ============================================================================
__global__ __launch_bounds__(256) void finalize_k(const float* __restrict__ part,
                                                  const float* __restrict__ rsum,
                                                  const float* __restrict__ mtb,
                                                  const float* __restrict__ lnw,
                                                  float* __restrict__ hout){
  const int sblk=blockIdx.x, head=blockIdx.y;
  const int bI=head>>2, nh=head&3;
  const int s0=sblk*32;
  const int t=threadIdx.x, row=t>>3, sub=t&7;
  __shared__ float red1[32][8], red2[32][8];
  __shared__ float mu_s[32], rs_s[32], inv_s[32];
  const size_t pbase=(size_t)head*2048+s0;
  const float* prow=part+(pbase+row)*336;
  float s1=0.f,s2=0.f;
  for(int c=sub;c<336;c+=8){ const float v=prow[c]; s1+=v; s2+=v*v; }
  red1[row][sub]=s1; red2[row][sub]=s2;
  __syncthreads();
  if(sub==0){
    float a1=0.f,a2=0.f;
#pragma unroll
    for(int j=0;j<8;j++){ a1+=red1[row][j]; a2+=red2[row][j]; }
    const float mt=mtb[(size_t)head*S_+s0+row];
    const float nn=fmaxf(fabsf(rsum[pbase+row]), expf(fminf(fmaxf(-mt,-60.f),60.f)));
    const float inv=1.f/(nn+1e-6f);
    const float mu=a1*inv/336.f;
    const float var=a2*inv*inv/336.f-mu*mu;
    inv_s[row]=inv; mu_s[row]=mu;
    rs_s[row]=rsqrtf(fmaxf(var,0.f)+1e-5f);
  }
  __syncthreads();
  const float inv=inv_s[row], mu=mu_s[row], rs=rs_s[row];
  float* orow=hout+((size_t)(bI*S_+s0+row))*H_+nh*DH_;
  for(int c=sub;c<336;c+=8)
    orow[c]=(prow[c]*inv-mu)*rs*lnw[nh*DH_+c];
}

// ---- h_state = (h_out + skip*act) * silu(z) ----
__global__ __launch_bounds__(256) void hstate_k(const float* __restrict__ hout,
                                                const float* __restrict__ act,
                                                const float* __restrict__ xin,
                                                const float* __restrict__ skip,
                                                float* __restrict__ hs){
  const int i=blockIdx.x*256+threadIdx.x;
  if(i>=(int)N_BSH) return;
  const int bs=i/H_, h=i-bs*H_;
  const float z=xin[(size_t)bs*H2_+H_+h];
  hs[(size_t)bs*H_+h]=(hout[(size_t)bs*H_+h]+skip[h]*act[(size_t)bs*H_+h])*siluf(z);
}

// ============================================================================
extern "C" void kernel_launch(void* const* d_in, const int* in_sizes, int n_in,
                              void* d_out, int out_size, void* d_ws, size_t ws_size,
                              hipStream_t stream){
  float* ws=(float*)d_ws;
  int* flag=(int*)ws;

  float* igb  = ws+O_IGB;
  float* logfb= ws+O_LOGF;
  float* ab   = ws+O_AB;
  float* Mbuf = ws+O_MB;
  float* mtb  = ws+O_MTB;
  float* f_ck = ws+O_CK;
  float* f_cb = ws+O_CB;
  float* f_wq = ws+O_WQ;
  float* f_wk = ws+O_WK;
  float* f_wv = ws+O_WV;
  float* f_wig= ws+O_WIG;
  float* f_big= ws+O_BIG;
  float* f_wfg= ws+O_WFG;
  float* f_bfg= ws+O_BFG;
  float* f_lnw= ws+O_LNW;
  float* f_skp= ws+O_SKP;
  float* xin  = ws+O_XIN;
  float* act  = ws+O_ACT;
  float* qb   = ws+O_QB;
  float* kb   = ws+O_KB;
  float* vb   = ws+O_VB;
  float* hout = ws+O_HOUT;
  float* hs   = qb;                            // alias: q dead after mlstm6_k

  unsigned short* xhi  =(unsigned short*)(ws+O_FX);   unsigned short* xlo  =xhi+N_X;
  unsigned short* wuphi=(unsigned short*)(ws+O_FWUP); unsigned short* wuplo=wuphi+N_WUP;
  unsigned short* wdnhi=(unsigned short*)(ws+O_FWDN); unsigned short* wdnlo=wdnhi+N_WDN;
  unsigned short* khi=(unsigned short*)(ws+O_FX);     // x/wup frags dead after up-gemm
  unsigned short* klo=khi+KSPLIT_SHORTS;
  unsigned short* vTf=(unsigned short*)kb;     // kb dead after gates+kprep
  unsigned short* hshi=(unsigned short*)kb;    // vTf dead after mlstm6_k
  unsigned short* hslo=hshi+N_BSH;
  float* partb=vb;                             // vb dead after vprep
  float* rsumb=igb;                            // igb dead after scan_k

  detect_k<<<1,256,0,stream>>>((const unsigned short*)d_in[0],flag);
  // fused weight conversions (11 tensors, one launch)
  convall_k<<<(CVT+255)/256,256,0,stream>>>(d_in[2],d_in[3],d_in[4],d_in[5],d_in[6],
                                            d_in[7],d_in[8],d_in[9],d_in[10],d_in[11],
                                            d_in[12],ws,flag);

  // up-GEMM: xin = x @ Wup  (M=4096,K=1024 kcn=32, N=2688)
  aprep_k<<<(256*32*64+255)/256,256,0,stream>>>(d_in[0],flag,32,1024,256*32*64,xhi,xlo);
  bprep_k<<<(168*32*64+255)/256,256,0,stream>>>(d_in[1],flag,32,2688,168*32*64,wuphi,wuplo);
  gemm2_k<<<dim3(2688/128,4096/128),256,0,stream>>>(xhi,xlo,wuphi,wuplo,xin,nullptr,32,H2_);

  conv_act_k<<<(int)((N_BSH+255)/256),256,0,stream>>>(xin,f_ck,f_cb,act);
  qkv_k<<<(int)((N_BSH+255)/256),256,0,stream>>>(act,xin,f_wq,f_wk,f_wv,qb,kb,vb);
  // gates v2: one wave per (b,s) row, 4096 waves
  gates2_k<<<(BS_*64+255)/256,256,0,stream>>>(qb,kb,vb,f_wig,f_big,f_wfg,f_bfg,igb,logfb);
  kprep_k<<<8*128,256,0,stream>>>(kb,khi,klo);
  vprep_k<<<8*64,256,0,stream>>>(vb,vTf);
  // wdn frags (independent; region untouched by khi/klo)
  bprep_k<<<(64*42*64+255)/256,256,0,stream>>>(d_in[13],flag,42,1024,64*42*64,wdnhi,wdnlo);
  scan_k<<<B_*NH_,256,0,stream>>>(igb,logfb,ab,Mbuf,mtb);
  hipMemsetAsync(partb,0,N_BSH*sizeof(float),stream);
  hipMemsetAsync(rsumb,0,(size_t)NG_*sizeof(float),stream);
  // mLSTM v12: 256 blocks x 512 thr = 8 heads x 8 pairs x 4 seg; 17 chunks each
  mlstm6_k<<<256,512,0,stream>>>(qb,khi,klo,vTf,ab,Mbuf,partb,rsumb);
  finalize_k<<<dim3(S_/32,B_*NH_),256,0,stream>>>(partb,rsumb,mtb,f_lnw,hout);
  hstate_k<<<(int)((N_BSH+255)/256),256,0,stream>>>(hout,act,xin,f_skp,hs);
  // down-GEMM: out = hs @ Wdn  (M=4096,K=1344 kcn=42, N=1024), direct to d_out
  aprep_k<<<(256*42*64+255)/256,256,0,stream>>>(hs,nullptr,42,1344,256*42*64,hshi,hslo);
  gemm2_k<<<dim3(1024/128,4096/128),256,0,stream>>>(hshi,hslo,wdnhi,wdnlo,d_out,flag,42,E_);
}